// Round 4
// baseline (9518.942 us; speedup 1.0000x reference)
//
#include <hip/hip_runtime.h>
#include <hip/hip_bf16.h>

typedef unsigned short u16;
typedef unsigned int u32;
typedef __attribute__((ext_vector_type(8))) __bf16 bf16x8;
typedef __attribute__((ext_vector_type(4))) float f32x4;

#define SEQ 4096
#define NBATCH 4
#define DMODEL 1024
#define DINNER 2048
#define DSTATE 128
#define NH 32
#define CONVD 2304
#define DPROJ 4384
#define ROWS (NBATCH*SEQ)   // 16384
#define TCH 256             // conv time-chunk
#define NCH (SEQ/TCH)       // 16 chunks -> 15 halo boundaries per batch

__device__ __forceinline__ float bf2f(u16 v) {
    u32 x = ((u32)v) << 16;
    float f;
    __builtin_memcpy(&f, &x, 4);
    return f;
}
__device__ __forceinline__ u16 f2bf(float f) {
    u32 x;
    __builtin_memcpy(&x, &f, 4);
    u32 r = (x + 0x7FFFu + ((x >> 16) & 1u)) >> 16;
    return (u16)r;
}
__device__ __forceinline__ void unpack8(uint4 v, float* f) {
    u32 w0 = v.x, w1 = v.y, w2 = v.z, w3 = v.w;
    f[0] = bf2f((u16)(w0 & 0xFFFF)); f[1] = bf2f((u16)(w0 >> 16));
    f[2] = bf2f((u16)(w1 & 0xFFFF)); f[3] = bf2f((u16)(w1 >> 16));
    f[4] = bf2f((u16)(w2 & 0xFFFF)); f[5] = bf2f((u16)(w2 >> 16));
    f[6] = bf2f((u16)(w3 & 0xFFFF)); f[7] = bf2f((u16)(w3 >> 16));
}

// ---------------- f32 -> bf16 weight panel conversion ----------------
__global__ __launch_bounds__(256) void cvt_kernel(
    const float* __restrict__ in, u16* __restrict__ out, int n)
{
    int i = (blockIdx.x * 256 + threadIdx.x) * 4;
    if (i < n) {
        float4 v = *(const float4*)(in + i);
        u16 o[4] = { f2bf(v.x), f2bf(v.y), f2bf(v.z), f2bf(v.w) };
        *(uint2*)(out + i) = *(const uint2*)o;
    }
}

// ---------------- embedding: f32 table -> bf16 rows ----------------
__global__ __launch_bounds__(256) void embed_kernel(
    const int* __restrict__ x, const float* __restrict__ emb, u16* __restrict__ h)
{
    int row = blockIdx.x, tid = threadIdx.x;
    int id = x[row];
    float4 v = *(const float4*)(emb + (size_t)id * DMODEL + tid * 4);
    u16 o[4] = { f2bf(v.x), f2bf(v.y), f2bf(v.z), f2bf(v.w) };
    *(uint2*)(h + (size_t)row * DMODEL + tid * 4) = *(const uint2*)o;
}

// ---------------- rmsnorm (bf16 in, f32 weight -> bf16 out) ----------------
__global__ __launch_bounds__(256) void rmsnorm_kernel(
    const u16* __restrict__ in, const float* __restrict__ w, u16* __restrict__ out)
{
    int row = blockIdx.x, tid = threadIdx.x;
    const u16* r = in + (size_t)row * DMODEL + tid * 4;
    float v[4];
    v[0] = bf2f(r[0]); v[1] = bf2f(r[1]); v[2] = bf2f(r[2]); v[3] = bf2f(r[3]);
    float s = v[0]*v[0] + v[1]*v[1] + v[2]*v[2] + v[3]*v[3];
    #pragma unroll
    for (int off = 32; off; off >>= 1) s += __shfl_xor(s, off);
    __shared__ float red[4];
    if ((tid & 63) == 0) red[tid >> 6] = s;
    __syncthreads();
    float tot = red[0] + red[1] + red[2] + red[3];
    float sc = rsqrtf(tot * (1.f / DMODEL) + 1e-5f);
    float4 wv = *(const float4*)(w + tid * 4);
    u16* o = out + (size_t)row * DMODEL + tid * 4;
    u16 ov[4] = { f2bf(v[0] * sc * wv.x), f2bf(v[1] * sc * wv.y),
                  f2bf(v[2] * sc * wv.z), f2bf(v[3] * sc * wv.w) };
    *(uint2*)o = *(const uint2*)ov;
}

// ---------------- NT GEMM: C[M,N] = A[M,K] @ B[N,K]^T, bf16 in, fp32 acc ----------------
// A row stride = lda (elements).
// EPI 0: store bf16 to Cb.  EPI 1: Cb += val (bf16 accumulate).  EPI 2: store f32 to Cf.
template<int EPI>
__global__ __launch_bounds__(256) void gemm_nt(
    const u16* __restrict__ A, const u16* __restrict__ B,
    int N, int K, int lda, int ntiles,
    u16* __restrict__ Cb, float* __restrict__ Cf)
{
    __shared__ __align__(16) u16 As[128 * 64];
    __shared__ __align__(16) u16 Bs[128 * 64];
    // 8-wide m-supertile swizzle for L2 reuse of the B panel
    const int GM = 8;
    int gsz = GM * ntiles;
    int bid = blockIdx.x;
    int grp = bid / gsz, rem = bid % gsz;
    int m0 = (grp * GM + (rem % GM)) * 128;
    int n0 = (rem / GM) * 128;

    int tid = threadIdx.x;
    int lane = tid & 63, wv = tid >> 6;
    int wm = wv & 1, wn = wv >> 1;
    int q = lane >> 4, mr = lane & 15;

    f32x4 acc[4][4];
    #pragma unroll
    for (int i = 0; i < 4; i++)
        #pragma unroll
        for (int j = 0; j < 4; j++) acc[i][j] = (f32x4){0.f, 0.f, 0.f, 0.f};

    int sr = tid >> 3;   // 0..31
    int sc = tid & 7;    // 16B chunk within 128B row

    for (int kt = 0; kt < K; kt += 64) {
        #pragma unroll
        for (int ps = 0; ps < 4; ++ps) {
            int r = ps * 32 + sr;
            int cs = sc ^ (r & 7);
            *(uint4*)&As[r * 64 + cs * 8] =
                *(const uint4*)(A + (size_t)(m0 + r) * lda + kt + sc * 8);
        }
        #pragma unroll
        for (int ps = 0; ps < 4; ++ps) {
            int r = ps * 32 + sr;
            int cs = sc ^ (r & 7);
            uint4 v; v.x = v.y = v.z = v.w = 0u;
            int gn = n0 + r;
            if (gn < N) v = *(const uint4*)(B + (size_t)gn * K + kt + sc * 8);
            *(uint4*)&Bs[r * 64 + cs * 8] = v;
        }
        __syncthreads();
        #pragma unroll
        for (int kk = 0; kk < 2; ++kk) {
            bf16x8 af[4], bfr[4];
            #pragma unroll
            for (int mi = 0; mi < 4; ++mi) {
                int r = wm * 64 + mi * 16 + mr;
                int c = (kk * 4 + q) ^ (r & 7);
                af[mi] = *(const bf16x8*)&As[r * 64 + c * 8];
            }
            #pragma unroll
            for (int ni = 0; ni < 4; ++ni) {
                int r = wn * 64 + ni * 16 + mr;
                int c = (kk * 4 + q) ^ (r & 7);
                bfr[ni] = *(const bf16x8*)&Bs[r * 64 + c * 8];
            }
            #pragma unroll
            for (int mi = 0; mi < 4; ++mi)
                #pragma unroll
                for (int ni = 0; ni < 4; ++ni)
                    acc[mi][ni] = __builtin_amdgcn_mfma_f32_16x16x32_bf16(
                        af[mi], bfr[ni], acc[mi][ni], 0, 0, 0);
        }
        __syncthreads();
    }

    // C/D layout: col = lane&15, row = quad*4 + reg  (m89-verified)
    #pragma unroll
    for (int mi = 0; mi < 4; ++mi) {
        #pragma unroll
        for (int ni = 0; ni < 4; ++ni) {
            int gn = n0 + wn * 64 + ni * 16 + mr;
            if (gn < N) {
                #pragma unroll
                for (int r4 = 0; r4 < 4; ++r4) {
                    int gm = m0 + wm * 64 + mi * 16 + q * 4 + r4;
                    float v = acc[mi][ni][r4];
                    size_t idx = (size_t)gm * N + gn;
                    if (EPI == 0)      Cb[idx] = f2bf(v);
                    else if (EPI == 1) Cb[idx] = f2bf(bf2f(Cb[idx]) + v);
                    else               Cf[idx] = v;
                }
            }
        }
    }
}

// ---------------- halo save: raw xBC boundary rows before in-place conv ----------------
__global__ __launch_bounds__(256) void halo_kernel(
    const u16* __restrict__ zx, u16* __restrict__ halo)
{
    int c = blockIdx.x * 256 + threadIdx.x;   // 0..2303
    int idx = blockIdx.y;                     // 0..(NCH-1)*3-1
    int b = blockIdx.z;
    int bi = idx / 3, r = idx % 3;            // boundary index, row-within-halo
    int t = (bi + 1) * TCH - 3 + r;
    halo[(((size_t)b * (NCH - 1) + bi) * 3 + r) * CONVD + c] =
        zx[((size_t)b * SEQ + t) * DPROJ + DINNER + c];
}

// ---------------- depthwise causal conv (taps=4, f32 weights) + silu, in-place ----------------
__global__ __launch_bounds__(256) void convip_kernel(
    u16* __restrict__ zx, const float* __restrict__ cw, const float* __restrict__ cb,
    const u16* __restrict__ halo)
{
    int c = blockIdx.x * 256 + threadIdx.x;   // 0..2303
    int ci = blockIdx.y;                      // time chunk
    int b = blockIdx.z;
    float w0 = cw[c * 4 + 0], w1 = cw[c * 4 + 1];
    float w2 = cw[c * 4 + 2], w3 = cw[c * 4 + 3];
    float bias = cb[c];
    float h3 = 0.f, h2 = 0.f, h1 = 0.f;       // x[t-3], x[t-2], x[t-1]
    if (ci > 0) {
        const u16* hb = halo + (((size_t)b * (NCH - 1) + (ci - 1)) * 3) * CONVD + c;
        h3 = bf2f(hb[0 * CONVD]);
        h2 = bf2f(hb[1 * CONVD]);
        h1 = bf2f(hb[2 * CONVD]);
    }
    u16* p = zx + ((size_t)b * SEQ + (size_t)ci * TCH) * DPROJ + DINNER + c;
    #pragma unroll 4
    for (int t = 0; t < TCH; ++t) {
        float xr = bf2f(*p);
        float v = bias + w0 * h3 + w1 * h2 + w2 * h1 + w3 * xr;
        *p = f2bf(v / (1.f + expf(-v)));
        h3 = h2; h2 = h1; h1 = xr;
        p += DPROJ;
    }
}

// ---------------- selective scan (recurrent, fp32 state in regs) ----------------
// grid (2, NH, NBATCH); block 256 = 32 p-values x 8 n-groups of 16 states
// reads conv'd x/B/C and raw dt from zx; writes y IN PLACE over the x columns
__global__ __launch_bounds__(256) void scan_kernel(
    u16* __restrict__ zx,
    const float* __restrict__ dtb, const float* __restrict__ Alog,
    const float* __restrict__ Dp)
{
    int ph = blockIdx.x;       // headdim half: p base = ph*32
    int hd = blockIdx.y;
    int b  = blockIdx.z;
    int tid = threadIdx.x;
    int p = tid >> 3;          // 0..31
    int g = tid & 7;           // n-group, 16 states each

    __shared__ __align__(16) u16 sB[8][128];
    __shared__ __align__(16) u16 sC[8][128];
    __shared__ __align__(16) u16 sx[8][32];
    __shared__ float sdt[8], sdA[8];

    float dtbF = dtb[hd];
    float Aneg = -expf(Alog[hd]);
    float Dh = Dp[hd];

    float hst[16];
    #pragma unroll
    for (int j = 0; j < 16; j++) hst[j] = 0.f;

    int tt0 = tid >> 5;        // staging row 0..7
    int l32 = tid & 31;
    const size_t rowbase = (size_t)b * SEQ;

    for (int t0 = 0; t0 < SEQ; t0 += 8) {
        __syncthreads();
        {
            const u16* rp = zx + (rowbase + t0 + tt0) * DPROJ;
            if (l32 < 16) *(uint4*)&sB[tt0][l32 * 8] = *(const uint4*)(rp + 2 * DINNER + l32 * 8);
            else          *(uint4*)&sC[tt0][(l32 - 16) * 8] = *(const uint4*)(rp + 2 * DINNER + DSTATE + (l32 - 16) * 8);
            if (l32 < 4)  *(uint4*)&sx[tt0][l32 * 8] = *(const uint4*)(rp + DINNER + hd * 64 + ph * 32 + l32 * 8);
            if (tid < 8) {
                int t = t0 + tid;
                float xx = bf2f(zx[(rowbase + t) * DPROJ + 2 * DINNER + 2 * DSTATE + hd]) + dtbF;
                float dtv = (xx > 20.f) ? xx : log1pf(expf(xx));
                sdt[tid] = dtv;
                sdA[tid] = expf(dtv * Aneg);
            }
        }
        __syncthreads();
        for (int tt = 0; tt < 8; ++tt) {
            float xv = bf2f(sx[tt][p]);
            float aa = sdA[tt];
            float s = sdt[tt] * xv;
            uint4 b0 = *(const uint4*)&sB[tt][g * 16];
            uint4 b1 = *(const uint4*)&sB[tt][g * 16 + 8];
            uint4 c0 = *(const uint4*)&sC[tt][g * 16];
            uint4 c1 = *(const uint4*)&sC[tt][g * 16 + 8];
            float Bv[16], Cv[16];
            unpack8(b0, Bv); unpack8(b1, Bv + 8);
            unpack8(c0, Cv); unpack8(c1, Cv + 8);
            float yp = 0.f;
            #pragma unroll
            for (int j = 0; j < 16; ++j) {
                hst[j] = fmaf(aa, hst[j], s * Bv[j]);
                yp = fmaf(hst[j], Cv[j], yp);
            }
            yp += __shfl_xor(yp, 1);
            yp += __shfl_xor(yp, 2);
            yp += __shfl_xor(yp, 4);
            if (g == 0)
                zx[(rowbase + t0 + tt) * DPROJ + DINNER + hd * 64 + ph * 32 + p]
                    = f2bf(yp + Dh * xv);
        }
    }
}

// ---------------- y * silu(z) then rmsnorm(gnorm_w f32); z and y both live in zx ----------------
__global__ __launch_bounds__(256) void gatenorm_kernel(
    u16* __restrict__ zx, const float* __restrict__ gw)
{
    int row = blockIdx.x, tid = threadIdx.x;
    u16* zr = zx + (size_t)row * DPROJ;
    float v[8];
    float s = 0.f;
    #pragma unroll
    for (int i = 0; i < 8; ++i) {
        int idx = i * 256 + tid;
        float zv = bf2f(zr[idx]);
        float gate = zv / (1.f + expf(-zv));
        float val = bf2f(zr[DINNER + idx]) * gate;
        v[i] = val;
        s += val * val;
    }
    #pragma unroll
    for (int off = 32; off; off >>= 1) s += __shfl_xor(s, off);
    __shared__ float red[4];
    if ((tid & 63) == 0) red[tid >> 6] = s;
    __syncthreads();
    float tot = red[0] + red[1] + red[2] + red[3];
    float sc = rsqrtf(tot * (1.f / DINNER) + 1e-5f);
    #pragma unroll
    for (int i = 0; i < 8; ++i) {
        int idx = i * 256 + tid;
        zr[DINNER + idx] = f2bf(v[i] * sc * gw[idx]);
    }
}

extern "C" void kernel_launch(void* const* d_in, const int* in_sizes, int n_in,
                              void* d_out, int out_size, void* d_ws, size_t ws_size,
                              hipStream_t stream) {
    const int*   x          = (const int*)d_in[0];
    const float* emb        = (const float*)d_in[1];
    const float* in_proj_w  = (const float*)d_in[2];
    const float* conv_w     = (const float*)d_in[3];
    const float* conv_b     = (const float*)d_in[4];
    const float* dt_bias    = (const float*)d_in[5];
    const float* A_log      = (const float*)d_in[6];
    const float* Dp         = (const float*)d_in[7];
    const float* gnorm_w    = (const float*)d_in[8];
    const float* out_proj_w = (const float*)d_in[9];
    const float* rms_w      = (const float*)d_in[10];
    const float* norm_f_w   = (const float*)d_in[11];
    const float* lm_head_w  = (const float*)d_in[12];
    float* out = (float*)d_out;

    // Workspace layout (total ~215 MB):
    //   h      : bf16 residual stream, 32 MB
    //   zx     : zxbcdt; xBC conv'd in place; y written over x columns, 137 MB
    //   normed : rmsnorm output, 32 MB (halo aliases it: normed dead after in_proj)
    //   wA     : bf16 copy of current in_proj panel (also lm_head at end), 9 MB
    //   wB     : bf16 copy of current out_proj panel, 4.2 MB
    char* w = (char*)d_ws;
    u16* h      = (u16*)w; w += (size_t)ROWS * DMODEL * 2;
    u16* zx     = (u16*)w; w += (size_t)ROWS * DPROJ * 2;
    u16* normed = (u16*)w; w += (size_t)ROWS * DMODEL * 2;
    u16* wA     = (u16*)w; w += (size_t)DPROJ * DMODEL * 2;
    u16* wB     = (u16*)w; w += (size_t)DMODEL * DINNER * 2;
    u16* halo   = normed;

    embed_kernel<<<ROWS, 256, 0, stream>>>(x, emb, h);

    const int nInW = DPROJ * DMODEL;    // 4,489,216
    const int nOutW = DMODEL * DINNER;  // 2,097,152
    const int nHeadW = 64 * DMODEL;     // 65,536

    for (int l = 0; l < 4; ++l) {
        cvt_kernel<<<nInW / 1024, 256, 0, stream>>>(
            in_proj_w + (size_t)l * nInW, wA, nInW);
        cvt_kernel<<<nOutW / 1024, 256, 0, stream>>>(
            out_proj_w + (size_t)l * nOutW, wB, nOutW);
        rmsnorm_kernel<<<ROWS, 256, 0, stream>>>(h, rms_w + l * DMODEL, normed);
        // zxbcdt = normed @ in_proj_w[l]^T   (N=4384 -> 35 n-tiles, last partial)
        gemm_nt<0><<<128 * 35, 256, 0, stream>>>(
            normed, wA, DPROJ, DMODEL, DMODEL, 35, zx, nullptr);
        halo_kernel<<<dim3(9, (NCH - 1) * 3, NBATCH), 256, 0, stream>>>(zx, halo);
        convip_kernel<<<dim3(9, NCH, NBATCH), 256, 0, stream>>>(
            zx, conv_w + (size_t)l * CONVD * 4, conv_b + (size_t)l * CONVD, halo);
        scan_kernel<<<dim3(2, NH, NBATCH), 256, 0, stream>>>(
            zx, dt_bias + l * NH, A_log + l * NH, Dp + l * NH);
        gatenorm_kernel<<<ROWS, 256, 0, stream>>>(zx, gnorm_w + (size_t)l * DINNER);
        // h += y @ out_proj_w[l]^T  (y lives at zx cols [2048,4096), lda=DPROJ)
        gemm_nt<1><<<128 * 8, 256, 0, stream>>>(
            zx + DINNER, wB, DMODEL, DINNER, DPROJ, 8, h, nullptr);
    }

    rmsnorm_kernel<<<ROWS, 256, 0, stream>>>(h, norm_f_w, normed);
    // logits = normed @ lm_head_w^T  (N=64, single guarded n-tile, f32 output)
    cvt_kernel<<<nHeadW / 1024, 256, 0, stream>>>(lm_head_w, wA, nHeadW);
    gemm_nt<2><<<128 * 1, 256, 0, stream>>>(
        normed, wA, 64, DMODEL, DMODEL, 1, nullptr, out);
}

// Round 5
// 6773.415 us; speedup vs baseline: 1.4053x; 1.4053x over previous
//
#include <hip/hip_runtime.h>
#include <hip/hip_bf16.h>

typedef unsigned short u16;
typedef unsigned int u32;
typedef __attribute__((ext_vector_type(8))) __bf16 bf16x8;
typedef __attribute__((ext_vector_type(4))) float f32x4;

#define SEQ 4096
#define NBATCH 4
#define DMODEL 1024
#define DINNER 2048
#define DSTATE 128
#define NH 32
#define CONVD 2304
#define DPROJ 4384
#define ROWS (NBATCH*SEQ)   // 16384
#define TCH 256             // conv time-chunk
#define NCH (SEQ/TCH)       // 16 chunks -> 15 halo boundaries per batch
#define CL 512              // scan chunk length
#define NCK (SEQ/CL)        // 8 scan chunks

__device__ __forceinline__ float bf2f(u16 v) {
    u32 x = ((u32)v) << 16;
    float f;
    __builtin_memcpy(&f, &x, 4);
    return f;
}
__device__ __forceinline__ u16 f2bf(float f) {
    u32 x;
    __builtin_memcpy(&x, &f, 4);
    u32 r = (x + 0x7FFFu + ((x >> 16) & 1u)) >> 16;
    return (u16)r;
}
__device__ __forceinline__ void unpack8(uint4 v, float* f) {
    u32 w0 = v.x, w1 = v.y, w2 = v.z, w3 = v.w;
    f[0] = bf2f((u16)(w0 & 0xFFFF)); f[1] = bf2f((u16)(w0 >> 16));
    f[2] = bf2f((u16)(w1 & 0xFFFF)); f[3] = bf2f((u16)(w1 >> 16));
    f[4] = bf2f((u16)(w2 & 0xFFFF)); f[5] = bf2f((u16)(w2 >> 16));
    f[6] = bf2f((u16)(w3 & 0xFFFF)); f[7] = bf2f((u16)(w3 >> 16));
}

// ---------------- f32 -> bf16 weight panel conversion ----------------
__global__ __launch_bounds__(256) void cvt_kernel(
    const float* __restrict__ in, u16* __restrict__ out, int n)
{
    int i = (blockIdx.x * 256 + threadIdx.x) * 4;
    if (i < n) {
        float4 v = *(const float4*)(in + i);
        u16 o[4] = { f2bf(v.x), f2bf(v.y), f2bf(v.z), f2bf(v.w) };
        *(uint2*)(out + i) = *(const uint2*)o;
    }
}

// ---------------- embedding: f32 table -> bf16 rows ----------------
__global__ __launch_bounds__(256) void embed_kernel(
    const int* __restrict__ x, const float* __restrict__ emb, u16* __restrict__ h)
{
    int row = blockIdx.x, tid = threadIdx.x;
    int id = x[row];
    float4 v = *(const float4*)(emb + (size_t)id * DMODEL + tid * 4);
    u16 o[4] = { f2bf(v.x), f2bf(v.y), f2bf(v.z), f2bf(v.w) };
    *(uint2*)(h + (size_t)row * DMODEL + tid * 4) = *(const uint2*)o;
}

// ---------------- rmsnorm (bf16 in, f32 weight -> bf16 out) ----------------
__global__ __launch_bounds__(256) void rmsnorm_kernel(
    const u16* __restrict__ in, const float* __restrict__ w, u16* __restrict__ out)
{
    int row = blockIdx.x, tid = threadIdx.x;
    const u16* r = in + (size_t)row * DMODEL + tid * 4;
    float v[4];
    v[0] = bf2f(r[0]); v[1] = bf2f(r[1]); v[2] = bf2f(r[2]); v[3] = bf2f(r[3]);
    float s = v[0]*v[0] + v[1]*v[1] + v[2]*v[2] + v[3]*v[3];
    #pragma unroll
    for (int off = 32; off; off >>= 1) s += __shfl_xor(s, off);
    __shared__ float red[4];
    if ((tid & 63) == 0) red[tid >> 6] = s;
    __syncthreads();
    float tot = red[0] + red[1] + red[2] + red[3];
    float sc = rsqrtf(tot * (1.f / DMODEL) + 1e-5f);
    float4 wv = *(const float4*)(w + tid * 4);
    u16* o = out + (size_t)row * DMODEL + tid * 4;
    u16 ov[4] = { f2bf(v[0] * sc * wv.x), f2bf(v[1] * sc * wv.y),
                  f2bf(v[2] * sc * wv.z), f2bf(v[3] * sc * wv.w) };
    *(uint2*)o = *(const uint2*)ov;
}

// ---------------- NT GEMM: C[M,N] = A[M,K] @ B[N,K]^T, bf16 in, fp32 acc ----------------
// A row stride = lda (elements).
// EPI 0: store bf16 to Cb.  EPI 1: Cb += val (bf16 accumulate).  EPI 2: store f32 to Cf.
template<int EPI>
__global__ __launch_bounds__(256) void gemm_nt(
    const u16* __restrict__ A, const u16* __restrict__ B,
    int N, int K, int lda, int ntiles,
    u16* __restrict__ Cb, float* __restrict__ Cf)
{
    __shared__ __align__(16) u16 As[128 * 64];
    __shared__ __align__(16) u16 Bs[128 * 64];
    // 8-wide m-supertile swizzle for L2 reuse of the B panel
    const int GM = 8;
    int gsz = GM * ntiles;
    int bid = blockIdx.x;
    int grp = bid / gsz, rem = bid % gsz;
    int m0 = (grp * GM + (rem % GM)) * 128;
    int n0 = (rem / GM) * 128;

    int tid = threadIdx.x;
    int lane = tid & 63, wv = tid >> 6;
    int wm = wv & 1, wn = wv >> 1;
    int q = lane >> 4, mr = lane & 15;

    f32x4 acc[4][4];
    #pragma unroll
    for (int i = 0; i < 4; i++)
        #pragma unroll
        for (int j = 0; j < 4; j++) acc[i][j] = (f32x4){0.f, 0.f, 0.f, 0.f};

    int sr = tid >> 3;   // 0..31
    int sc = tid & 7;    // 16B chunk within 128B row

    for (int kt = 0; kt < K; kt += 64) {
        #pragma unroll
        for (int ps = 0; ps < 4; ++ps) {
            int r = ps * 32 + sr;
            int cs = sc ^ (r & 7);
            *(uint4*)&As[r * 64 + cs * 8] =
                *(const uint4*)(A + (size_t)(m0 + r) * lda + kt + sc * 8);
        }
        #pragma unroll
        for (int ps = 0; ps < 4; ++ps) {
            int r = ps * 32 + sr;
            int cs = sc ^ (r & 7);
            uint4 v; v.x = v.y = v.z = v.w = 0u;
            int gn = n0 + r;
            if (gn < N) v = *(const uint4*)(B + (size_t)gn * K + kt + sc * 8);
            *(uint4*)&Bs[r * 64 + cs * 8] = v;
        }
        __syncthreads();
        #pragma unroll
        for (int kk = 0; kk < 2; ++kk) {
            bf16x8 af[4], bfr[4];
            #pragma unroll
            for (int mi = 0; mi < 4; ++mi) {
                int r = wm * 64 + mi * 16 + mr;
                int c = (kk * 4 + q) ^ (r & 7);
                af[mi] = *(const bf16x8*)&As[r * 64 + c * 8];
            }
            #pragma unroll
            for (int ni = 0; ni < 4; ++ni) {
                int r = wn * 64 + ni * 16 + mr;
                int c = (kk * 4 + q) ^ (r & 7);
                bfr[ni] = *(const bf16x8*)&Bs[r * 64 + c * 8];
            }
            #pragma unroll
            for (int mi = 0; mi < 4; ++mi)
                #pragma unroll
                for (int ni = 0; ni < 4; ++ni)
                    acc[mi][ni] = __builtin_amdgcn_mfma_f32_16x16x32_bf16(
                        af[mi], bfr[ni], acc[mi][ni], 0, 0, 0);
        }
        __syncthreads();
    }

    // C/D layout: col = lane&15, row = quad*4 + reg  (m89-verified)
    #pragma unroll
    for (int mi = 0; mi < 4; ++mi) {
        #pragma unroll
        for (int ni = 0; ni < 4; ++ni) {
            int gn = n0 + wn * 64 + ni * 16 + mr;
            if (gn < N) {
                #pragma unroll
                for (int r4 = 0; r4 < 4; ++r4) {
                    int gm = m0 + wm * 64 + mi * 16 + q * 4 + r4;
                    float v = acc[mi][ni][r4];
                    size_t idx = (size_t)gm * N + gn;
                    if (EPI == 0)      Cb[idx] = f2bf(v);
                    else if (EPI == 1) Cb[idx] = f2bf(bf2f(Cb[idx]) + v);
                    else               Cf[idx] = v;
                }
            }
        }
    }
}

// ---------------- halo save: raw xBC boundary rows before in-place conv ----------------
__global__ __launch_bounds__(256) void halo_kernel(
    const u16* __restrict__ zx, u16* __restrict__ halo)
{
    int c = blockIdx.x * 256 + threadIdx.x;   // 0..2303
    int idx = blockIdx.y;                     // 0..(NCH-1)*3-1
    int b = blockIdx.z;
    int bi = idx / 3, r = idx % 3;            // boundary index, row-within-halo
    int t = (bi + 1) * TCH - 3 + r;
    halo[(((size_t)b * (NCH - 1) + bi) * 3 + r) * CONVD + c] =
        zx[((size_t)b * SEQ + t) * DPROJ + DINNER + c];
}

// ---------------- depthwise causal conv (taps=4, f32 weights) + silu, in-place ----------------
__global__ __launch_bounds__(256) void convip_kernel(
    u16* __restrict__ zx, const float* __restrict__ cw, const float* __restrict__ cb,
    const u16* __restrict__ halo)
{
    int c = blockIdx.x * 256 + threadIdx.x;   // 0..2303
    int ci = blockIdx.y;                      // time chunk
    int b = blockIdx.z;
    float w0 = cw[c * 4 + 0], w1 = cw[c * 4 + 1];
    float w2 = cw[c * 4 + 2], w3 = cw[c * 4 + 3];
    float bias = cb[c];
    float h3 = 0.f, h2 = 0.f, h1 = 0.f;       // x[t-3], x[t-2], x[t-1]
    if (ci > 0) {
        const u16* hb = halo + (((size_t)b * (NCH - 1) + (ci - 1)) * 3) * CONVD + c;
        h3 = bf2f(hb[0 * CONVD]);
        h2 = bf2f(hb[1 * CONVD]);
        h1 = bf2f(hb[2 * CONVD]);
    }
    u16* p = zx + ((size_t)b * SEQ + (size_t)ci * TCH) * DPROJ + DINNER + c;
    #pragma unroll 4
    for (int t = 0; t < TCH; ++t) {
        float xr = bf2f(*p);
        float v = bias + w0 * h3 + w1 * h2 + w2 * h1 + w3 * xr;
        *p = f2bf(v / (1.f + expf(-v)));
        h3 = h2; h2 = h1; h1 = xr;
        p += DPROJ;
    }
}

// ---------------- pass 1: per-chunk local end-state S_c (h0 = 0), plus per-chunk sum(dt) ----------------
// grid ((NCK-1)*2, NH, NBATCH); block 256 = 32 p x 8 g(16 states)
__global__ __launch_bounds__(256) void chunkstate_kernel(
    const u16* __restrict__ zx,
    const float* __restrict__ dtb, const float* __restrict__ Alog,
    float* __restrict__ cs, float* __restrict__ dtsum)
{
    int ckph = blockIdx.x;
    int ck = ckph >> 1, ph = ckph & 1;
    int hd = blockIdx.y;
    int b  = blockIdx.z;
    int tid = threadIdx.x;
    int p = tid >> 3;
    int g = tid & 7;

    __shared__ __align__(16) u16 sB[8][128];
    __shared__ __align__(16) u16 sx[8][32];
    __shared__ float sdt[8], sdA[8];

    float dtbF = dtb[hd];
    float Aneg = -expf(Alog[hd]);

    float hst[16];
    #pragma unroll
    for (int j = 0; j < 16; j++) hst[j] = 0.f;
    float dtacc = 0.f;

    int tt0 = tid >> 5;
    int l32 = tid & 31;
    const size_t rowbase = (size_t)b * SEQ;

    for (int t0 = ck * CL; t0 < (ck + 1) * CL; t0 += 8) {
        __syncthreads();
        {
            const u16* rp = zx + (rowbase + t0 + tt0) * DPROJ;
            if (l32 < 16) *(uint4*)&sB[tt0][l32 * 8] = *(const uint4*)(rp + 2 * DINNER + l32 * 8);
            if (l32 < 4)  *(uint4*)&sx[tt0][l32 * 8] = *(const uint4*)(rp + DINNER + hd * 64 + ph * 32 + l32 * 8);
            if (tid < 8) {
                int t = t0 + tid;
                float xx = bf2f(zx[(rowbase + t) * DPROJ + 2 * DINNER + 2 * DSTATE + hd]) + dtbF;
                float dtv = (xx > 20.f) ? xx : log1pf(expf(xx));
                sdt[tid] = dtv;
                sdA[tid] = expf(dtv * Aneg);
                dtacc += dtv;
            }
        }
        __syncthreads();
        for (int tt = 0; tt < 8; ++tt) {
            float xv = bf2f(sx[tt][p]);
            float aa = sdA[tt];
            float s = sdt[tt] * xv;
            uint4 b0 = *(const uint4*)&sB[tt][g * 16];
            uint4 b1 = *(const uint4*)&sB[tt][g * 16 + 8];
            float Bv[16];
            unpack8(b0, Bv); unpack8(b1, Bv + 8);
            #pragma unroll
            for (int j = 0; j < 16; ++j)
                hst[j] = fmaf(aa, hst[j], s * Bv[j]);
        }
    }

    float* cp = cs + (((size_t)b * NH + hd) * NCK + ck) * (64 * DSTATE)
              + (size_t)(ph * 32 + p) * DSTATE + g * 16;
    #pragma unroll
    for (int j = 0; j < 4; ++j)
        *(float4*)(cp + j * 4) = make_float4(hst[j*4+0], hst[j*4+1], hst[j*4+2], hst[j*4+3]);

    if (ph == 0 && tid < 8) {
        float s = dtacc;
        s += __shfl_xor(s, 1);
        s += __shfl_xor(s, 2);
        s += __shfl_xor(s, 4);
        if (tid == 0) dtsum[((size_t)b * NH + hd) * NCK + ck] = s;
    }
}

// ---------------- pass 3: chunk-parallel scan; h_start from weighted chunk states ----------------
// grid (NCK*2, NH, NBATCH); writes y IN PLACE over the x columns of zx
__global__ __launch_bounds__(256) void scan_kernel(
    u16* __restrict__ zx,
    const float* __restrict__ dtb, const float* __restrict__ Alog,
    const float* __restrict__ Dp,
    const float* __restrict__ cs, const float* __restrict__ dtsum)
{
    int ckph = blockIdx.x;
    int ck = ckph >> 1, ph = ckph & 1;
    int hd = blockIdx.y;
    int b  = blockIdx.z;
    int tid = threadIdx.x;
    int p = tid >> 3;          // 0..31
    int g = tid & 7;           // n-group, 16 states each

    __shared__ __align__(16) u16 sB[8][128];
    __shared__ __align__(16) u16 sC[8][128];
    __shared__ __align__(16) u16 sx[8][32];
    __shared__ float sdt[8], sdA[8];

    float dtbF = dtb[hd];
    float Aneg = -expf(Alog[hd]);
    float Dh = Dp[hd];

    float hst[16];
    #pragma unroll
    for (int j = 0; j < 16; j++) hst[j] = 0.f;

    // h_start(ck) = sum_{c<ck} exp(Aneg * sum_{m=c+1}^{ck-1} dtsum[m]) * S_c
    if (ck > 0) {
        const float* dts = dtsum + ((size_t)b * NH + hd) * NCK;
        float suf = 0.f;
        for (int c = ck - 1; c >= 0; --c) {
            float e = Aneg * suf;
            if (e < -60.f) break;           // fully decayed; weights only shrink
            float wgt = expf(e);
            const float* cp = cs + (((size_t)b * NH + hd) * NCK + c) * (64 * DSTATE)
                            + (size_t)(ph * 32 + p) * DSTATE + g * 16;
            #pragma unroll
            for (int j = 0; j < 4; ++j) {
                float4 v = *(const float4*)(cp + j * 4);
                hst[j*4+0] = fmaf(wgt, v.x, hst[j*4+0]);
                hst[j*4+1] = fmaf(wgt, v.y, hst[j*4+1]);
                hst[j*4+2] = fmaf(wgt, v.z, hst[j*4+2]);
                hst[j*4+3] = fmaf(wgt, v.w, hst[j*4+3]);
            }
            suf += dts[c];
        }
    }

    int tt0 = tid >> 5;        // staging row 0..7
    int l32 = tid & 31;
    const size_t rowbase = (size_t)b * SEQ;

    for (int t0 = ck * CL; t0 < (ck + 1) * CL; t0 += 8) {
        __syncthreads();
        {
            const u16* rp = zx + (rowbase + t0 + tt0) * DPROJ;
            if (l32 < 16) *(uint4*)&sB[tt0][l32 * 8] = *(const uint4*)(rp + 2 * DINNER + l32 * 8);
            else          *(uint4*)&sC[tt0][(l32 - 16) * 8] = *(const uint4*)(rp + 2 * DINNER + DSTATE + (l32 - 16) * 8);
            if (l32 < 4)  *(uint4*)&sx[tt0][l32 * 8] = *(const uint4*)(rp + DINNER + hd * 64 + ph * 32 + l32 * 8);
            if (tid < 8) {
                int t = t0 + tid;
                float xx = bf2f(zx[(rowbase + t) * DPROJ + 2 * DINNER + 2 * DSTATE + hd]) + dtbF;
                float dtv = (xx > 20.f) ? xx : log1pf(expf(xx));
                sdt[tid] = dtv;
                sdA[tid] = expf(dtv * Aneg);
            }
        }
        __syncthreads();
        for (int tt = 0; tt < 8; ++tt) {
            float xv = bf2f(sx[tt][p]);
            float aa = sdA[tt];
            float s = sdt[tt] * xv;
            uint4 b0 = *(const uint4*)&sB[tt][g * 16];
            uint4 b1 = *(const uint4*)&sB[tt][g * 16 + 8];
            uint4 c0 = *(const uint4*)&sC[tt][g * 16];
            uint4 c1 = *(const uint4*)&sC[tt][g * 16 + 8];
            float Bv[16], Cv[16];
            unpack8(b0, Bv); unpack8(b1, Bv + 8);
            unpack8(c0, Cv); unpack8(c1, Cv + 8);
            float yp = 0.f;
            #pragma unroll
            for (int j = 0; j < 16; ++j) {
                hst[j] = fmaf(aa, hst[j], s * Bv[j]);
                yp = fmaf(hst[j], Cv[j], yp);
            }
            yp += __shfl_xor(yp, 1);
            yp += __shfl_xor(yp, 2);
            yp += __shfl_xor(yp, 4);
            if (g == 0)
                zx[(rowbase + t0 + tt) * DPROJ + DINNER + hd * 64 + ph * 32 + p]
                    = f2bf(yp + Dh * xv);
        }
    }
}

// ---------------- y * silu(z) then rmsnorm(gnorm_w f32); z and y both live in zx ----------------
__global__ __launch_bounds__(256) void gatenorm_kernel(
    u16* __restrict__ zx, const float* __restrict__ gw)
{
    int row = blockIdx.x, tid = threadIdx.x;
    u16* zr = zx + (size_t)row * DPROJ;
    float v[8];
    float s = 0.f;
    #pragma unroll
    for (int i = 0; i < 8; ++i) {
        int idx = i * 256 + tid;
        float zv = bf2f(zr[idx]);
        float gate = zv / (1.f + expf(-zv));
        float val = bf2f(zr[DINNER + idx]) * gate;
        v[i] = val;
        s += val * val;
    }
    #pragma unroll
    for (int off = 32; off; off >>= 1) s += __shfl_xor(s, off);
    __shared__ float red[4];
    if ((tid & 63) == 0) red[tid >> 6] = s;
    __syncthreads();
    float tot = red[0] + red[1] + red[2] + red[3];
    float sc = rsqrtf(tot * (1.f / DINNER) + 1e-5f);
    #pragma unroll
    for (int i = 0; i < 8; ++i) {
        int idx = i * 256 + tid;
        zr[DINNER + idx] = f2bf(v[i] * sc * gw[idx]);
    }
}

extern "C" void kernel_launch(void* const* d_in, const int* in_sizes, int n_in,
                              void* d_out, int out_size, void* d_ws, size_t ws_size,
                              hipStream_t stream) {
    const int*   x          = (const int*)d_in[0];
    const float* emb        = (const float*)d_in[1];
    const float* in_proj_w  = (const float*)d_in[2];
    const float* conv_w     = (const float*)d_in[3];
    const float* conv_b     = (const float*)d_in[4];
    const float* dt_bias    = (const float*)d_in[5];
    const float* A_log      = (const float*)d_in[6];
    const float* Dp         = (const float*)d_in[7];
    const float* gnorm_w    = (const float*)d_in[8];
    const float* out_proj_w = (const float*)d_in[9];
    const float* rms_w      = (const float*)d_in[10];
    const float* norm_f_w   = (const float*)d_in[11];
    const float* lm_head_w  = (const float*)d_in[12];
    float* out = (float*)d_out;

    // Workspace layout (~215.4 MB + 4KB):
    //   h       : bf16 residual stream, 32 MiB
    //   zx      : zxbcdt; xBC conv'd in place; y written over x cols, 137 MB
    //   scratch : 32 MiB, time-multiplexed:
    //             - normed (rmsnorm out; dead after in_proj GEMM)
    //             - halo (conv boundary rows; dead after conv)
    //             - cs = chunk states [b][h][ck][64][128] fp32 = exactly 32 MiB
    //               (written by chunkstate, read by scan, dead after scan)
    //   wA / wB : bf16 weight panels
    //   dtsum   : per-chunk sum(dt) [b][h][ck], 4 KB
    char* w = (char*)d_ws;
    u16* h       = (u16*)w; w += (size_t)ROWS * DMODEL * 2;
    u16* zx      = (u16*)w; w += (size_t)ROWS * DPROJ * 2;
    char* scratch = w;      w += (size_t)NBATCH * NH * NCK * 64 * DSTATE * 4;
    u16* wA      = (u16*)w; w += (size_t)DPROJ * DMODEL * 2;
    u16* wB      = (u16*)w; w += (size_t)DMODEL * DINNER * 2;
    float* dtsum = (float*)w; w += (size_t)NBATCH * NH * NCK * 4;
    u16* normed  = (u16*)scratch;
    u16* halo    = (u16*)scratch;
    float* cs    = (float*)scratch;

    embed_kernel<<<ROWS, 256, 0, stream>>>(x, emb, h);

    const int nInW = DPROJ * DMODEL;    // 4,489,216
    const int nOutW = DMODEL * DINNER;  // 2,097,152
    const int nHeadW = 64 * DMODEL;     // 65,536

    for (int l = 0; l < 4; ++l) {
        cvt_kernel<<<nInW / 1024, 256, 0, stream>>>(
            in_proj_w + (size_t)l * nInW, wA, nInW);
        cvt_kernel<<<nOutW / 1024, 256, 0, stream>>>(
            out_proj_w + (size_t)l * nOutW, wB, nOutW);
        rmsnorm_kernel<<<ROWS, 256, 0, stream>>>(h, rms_w + l * DMODEL, normed);
        // zxbcdt = normed @ in_proj_w[l]^T   (N=4384 -> 35 n-tiles, last partial)
        gemm_nt<0><<<128 * 35, 256, 0, stream>>>(
            normed, wA, DPROJ, DMODEL, DMODEL, 35, zx, nullptr);
        halo_kernel<<<dim3(9, (NCH - 1) * 3, NBATCH), 256, 0, stream>>>(zx, halo);
        convip_kernel<<<dim3(9, NCH, NBATCH), 256, 0, stream>>>(
            zx, conv_w + (size_t)l * CONVD * 4, conv_b + (size_t)l * CONVD, halo);
        // chunk-parallel scan: pass 1 (local chunk states) then pass 3 (scan w/ h_start)
        chunkstate_kernel<<<dim3((NCK - 1) * 2, NH, NBATCH), 256, 0, stream>>>(
            zx, dt_bias + l * NH, A_log + l * NH, cs, dtsum);
        scan_kernel<<<dim3(NCK * 2, NH, NBATCH), 256, 0, stream>>>(
            zx, dt_bias + l * NH, A_log + l * NH, Dp + l * NH, cs, dtsum);
        gatenorm_kernel<<<ROWS, 256, 0, stream>>>(zx, gnorm_w + (size_t)l * DINNER);
        // h += y @ out_proj_w[l]^T  (y lives at zx cols [2048,4096), lda=DPROJ)
        gemm_nt<1><<<128 * 8, 256, 0, stream>>>(
            zx + DINNER, wB, DMODEL, DINNER, DPROJ, 8, h, nullptr);
    }

    rmsnorm_kernel<<<ROWS, 256, 0, stream>>>(h, norm_f_w, normed);
    // logits = normed @ lm_head_w^T  (N=64, single guarded n-tile, f32 output)
    cvt_kernel<<<nHeadW / 1024, 256, 0, stream>>>(lm_head_w, wA, nHeadW);
    gemm_nt<2><<<128 * 1, 256, 0, stream>>>(
        normed, wA, 64, DMODEL, DMODEL, 1, nullptr, out);
}

// Round 6
// 3607.595 us; speedup vs baseline: 2.6386x; 1.8775x over previous
//
#include <hip/hip_runtime.h>
#include <hip/hip_bf16.h>

typedef unsigned short u16;
typedef unsigned int u32;
typedef __attribute__((ext_vector_type(8))) __bf16 bf16x8;
typedef __attribute__((ext_vector_type(4))) float f32x4;

#define SEQ 4096
#define NBATCH 4
#define DMODEL 1024
#define DINNER 2048
#define DSTATE 128
#define NH 32
#define CONVD 2304
#define DPROJ 4384
#define ROWS (NBATCH*SEQ)   // 16384
#define TCH 256             // conv time-chunk
#define NCH (SEQ/TCH)       // 16 chunks -> 15 halo boundaries per batch
#define QS 256              // SSD chunk length
#define NQ (SEQ/QS)         // 16 SSD chunks
#define XOFF DINNER                   // 2048: conv'd x columns
#define BOFF (2*DINNER)               // 4096: B columns
#define COFF (2*DINNER + DSTATE)      // 4224: C columns
#define DTOFF (2*DINNER + 2*DSTATE)   // 4352: dt columns

__device__ __forceinline__ float bf2f(u16 v) {
    u32 x = ((u32)v) << 16;
    float f;
    __builtin_memcpy(&f, &x, 4);
    return f;
}
__device__ __forceinline__ u16 f2bf(float f) {
    u32 x;
    __builtin_memcpy(&x, &f, 4);
    u32 r = (x + 0x7FFFu + ((x >> 16) & 1u)) >> 16;
    return (u16)r;
}
__device__ __forceinline__ void unpack8(uint4 v, float* f) {
    u32 w0 = v.x, w1 = v.y, w2 = v.z, w3 = v.w;
    f[0] = bf2f((u16)(w0 & 0xFFFF)); f[1] = bf2f((u16)(w0 >> 16));
    f[2] = bf2f((u16)(w1 & 0xFFFF)); f[3] = bf2f((u16)(w1 >> 16));
    f[4] = bf2f((u16)(w2 & 0xFFFF)); f[5] = bf2f((u16)(w2 >> 16));
    f[6] = bf2f((u16)(w3 & 0xFFFF)); f[7] = bf2f((u16)(w3 >> 16));
}

// ---------------- f32 -> bf16 weight panel conversion ----------------
__global__ __launch_bounds__(256) void cvt_kernel(
    const float* __restrict__ in, u16* __restrict__ out, int n)
{
    int i = (blockIdx.x * 256 + threadIdx.x) * 4;
    if (i < n) {
        float4 v = *(const float4*)(in + i);
        u16 o[4] = { f2bf(v.x), f2bf(v.y), f2bf(v.z), f2bf(v.w) };
        *(uint2*)(out + i) = *(const uint2*)o;
    }
}

// ---------------- embedding: f32 table -> bf16 rows ----------------
__global__ __launch_bounds__(256) void embed_kernel(
    const int* __restrict__ x, const float* __restrict__ emb, u16* __restrict__ h)
{
    int row = blockIdx.x, tid = threadIdx.x;
    int id = x[row];
    float4 v = *(const float4*)(emb + (size_t)id * DMODEL + tid * 4);
    u16 o[4] = { f2bf(v.x), f2bf(v.y), f2bf(v.z), f2bf(v.w) };
    *(uint2*)(h + (size_t)row * DMODEL + tid * 4) = *(const uint2*)o;
}

// ---------------- rmsnorm (bf16 in, f32 weight -> bf16 out) ----------------
__global__ __launch_bounds__(256) void rmsnorm_kernel(
    const u16* __restrict__ in, const float* __restrict__ w, u16* __restrict__ out)
{
    int row = blockIdx.x, tid = threadIdx.x;
    const u16* r = in + (size_t)row * DMODEL + tid * 4;
    float v[4];
    v[0] = bf2f(r[0]); v[1] = bf2f(r[1]); v[2] = bf2f(r[2]); v[3] = bf2f(r[3]);
    float s = v[0]*v[0] + v[1]*v[1] + v[2]*v[2] + v[3]*v[3];
    #pragma unroll
    for (int off = 32; off; off >>= 1) s += __shfl_xor(s, off);
    __shared__ float red[4];
    if ((tid & 63) == 0) red[tid >> 6] = s;
    __syncthreads();
    float tot = red[0] + red[1] + red[2] + red[3];
    float sc = rsqrtf(tot * (1.f / DMODEL) + 1e-5f);
    float4 wv = *(const float4*)(w + tid * 4);
    u16* o = out + (size_t)row * DMODEL + tid * 4;
    u16 ov[4] = { f2bf(v[0] * sc * wv.x), f2bf(v[1] * sc * wv.y),
                  f2bf(v[2] * sc * wv.z), f2bf(v[3] * sc * wv.w) };
    *(uint2*)o = *(const uint2*)ov;
}

// ---------------- NT GEMM: C[M,N] = A[M,K] @ B[N,K]^T, bf16 in, fp32 acc ----------------
template<int EPI>
__global__ __launch_bounds__(256) void gemm_nt(
    const u16* __restrict__ A, const u16* __restrict__ B,
    int N, int K, int lda, int ntiles,
    u16* __restrict__ Cb, float* __restrict__ Cf)
{
    __shared__ __align__(16) u16 As[128 * 64];
    __shared__ __align__(16) u16 Bs[128 * 64];
    const int GM = 8;
    int gsz = GM * ntiles;
    int bid = blockIdx.x;
    int grp = bid / gsz, rem = bid % gsz;
    int m0 = (grp * GM + (rem % GM)) * 128;
    int n0 = (rem / GM) * 128;

    int tid = threadIdx.x;
    int lane = tid & 63, wv = tid >> 6;
    int wm = wv & 1, wn = wv >> 1;
    int q = lane >> 4, mr = lane & 15;

    f32x4 acc[4][4];
    #pragma unroll
    for (int i = 0; i < 4; i++)
        #pragma unroll
        for (int j = 0; j < 4; j++) acc[i][j] = (f32x4){0.f, 0.f, 0.f, 0.f};

    int sr = tid >> 3;
    int sc = tid & 7;

    for (int kt = 0; kt < K; kt += 64) {
        #pragma unroll
        for (int ps = 0; ps < 4; ++ps) {
            int r = ps * 32 + sr;
            int cs = sc ^ (r & 7);
            *(uint4*)&As[r * 64 + cs * 8] =
                *(const uint4*)(A + (size_t)(m0 + r) * lda + kt + sc * 8);
        }
        #pragma unroll
        for (int ps = 0; ps < 4; ++ps) {
            int r = ps * 32 + sr;
            int cs = sc ^ (r & 7);
            uint4 v; v.x = v.y = v.z = v.w = 0u;
            int gn = n0 + r;
            if (gn < N) v = *(const uint4*)(B + (size_t)gn * K + kt + sc * 8);
            *(uint4*)&Bs[r * 64 + cs * 8] = v;
        }
        __syncthreads();
        #pragma unroll
        for (int kk = 0; kk < 2; ++kk) {
            bf16x8 af[4], bfr[4];
            #pragma unroll
            for (int mi = 0; mi < 4; ++mi) {
                int r = wm * 64 + mi * 16 + mr;
                int c = (kk * 4 + q) ^ (r & 7);
                af[mi] = *(const bf16x8*)&As[r * 64 + c * 8];
            }
            #pragma unroll
            for (int ni = 0; ni < 4; ++ni) {
                int r = wn * 64 + ni * 16 + mr;
                int c = (kk * 4 + q) ^ (r & 7);
                bfr[ni] = *(const bf16x8*)&Bs[r * 64 + c * 8];
            }
            #pragma unroll
            for (int mi = 0; mi < 4; ++mi)
                #pragma unroll
                for (int ni = 0; ni < 4; ++ni)
                    acc[mi][ni] = __builtin_amdgcn_mfma_f32_16x16x32_bf16(
                        af[mi], bfr[ni], acc[mi][ni], 0, 0, 0);
        }
        __syncthreads();
    }

    #pragma unroll
    for (int mi = 0; mi < 4; ++mi) {
        #pragma unroll
        for (int ni = 0; ni < 4; ++ni) {
            int gn = n0 + wn * 64 + ni * 16 + mr;
            if (gn < N) {
                #pragma unroll
                for (int r4 = 0; r4 < 4; ++r4) {
                    int gm = m0 + wm * 64 + mi * 16 + q * 4 + r4;
                    float v = acc[mi][ni][r4];
                    size_t idx = (size_t)gm * N + gn;
                    if (EPI == 0)      Cb[idx] = f2bf(v);
                    else if (EPI == 1) Cb[idx] = f2bf(bf2f(Cb[idx]) + v);
                    else               Cf[idx] = v;
                }
            }
        }
    }
}

// ---------------- halo save ----------------
__global__ __launch_bounds__(256) void halo_kernel(
    const u16* __restrict__ zx, u16* __restrict__ halo)
{
    int c = blockIdx.x * 256 + threadIdx.x;
    int idx = blockIdx.y;
    int b = blockIdx.z;
    int bi = idx / 3, r = idx % 3;
    int t = (bi + 1) * TCH - 3 + r;
    halo[(((size_t)b * (NCH - 1) + bi) * 3 + r) * CONVD + c] =
        zx[((size_t)b * SEQ + t) * DPROJ + DINNER + c];
}

// ---------------- depthwise causal conv + silu, in-place ----------------
__global__ __launch_bounds__(256) void convip_kernel(
    u16* __restrict__ zx, const float* __restrict__ cw, const float* __restrict__ cb,
    const u16* __restrict__ halo)
{
    int c = blockIdx.x * 256 + threadIdx.x;
    int ci = blockIdx.y;
    int b = blockIdx.z;
    float w0 = cw[c * 4 + 0], w1 = cw[c * 4 + 1];
    float w2 = cw[c * 4 + 2], w3 = cw[c * 4 + 3];
    float bias = cb[c];
    float h3 = 0.f, h2 = 0.f, h1 = 0.f;
    if (ci > 0) {
        const u16* hb = halo + (((size_t)b * (NCH - 1) + (ci - 1)) * 3) * CONVD + c;
        h3 = bf2f(hb[0 * CONVD]);
        h2 = bf2f(hb[1 * CONVD]);
        h1 = bf2f(hb[2 * CONVD]);
    }
    u16* p = zx + ((size_t)b * SEQ + (size_t)ci * TCH) * DPROJ + DINNER + c;
    #pragma unroll 4
    for (int t = 0; t < TCH; ++t) {
        float xr = bf2f(*p);
        float v = bias + w0 * h3 + w1 * h2 + w2 * h1 + w3 * xr;
        *p = f2bf(v / (1.f + expf(-v)));
        h3 = h2; h2 = h1; h1 = xr;
        p += DPROJ;
    }
}

// ================= SSD pass 1: per-chunk Hinc = Bw^T @ X (MFMA), dt cumsum =================
// grid (NQ, NH, NBATCH), 256 threads. Outputs: cs (Hinc bf16 [p][n]), scum_g, sdt_g, dAck.
__global__ __launch_bounds__(256) void ssd_p1(
    const u16* __restrict__ zx,
    const float* __restrict__ dtb, const float* __restrict__ Alog,
    u16* __restrict__ cs, float* __restrict__ scum_g, float* __restrict__ sdt_g,
    float* __restrict__ dAck)
{
    int ck = blockIdx.x, hd = blockIdx.y, b = blockIdx.z;
    int tid = threadIdx.x;
    int wv = tid >> 6, lane = tid & 63, q = lane >> 4, mr = lane & 15;

    __shared__ __align__(16) u16 BwT[128 * 136];
    __shared__ __align__(16) u16 XT1[64 * 136];
    __shared__ float scumL[256], sdtL[256], swL[256];

    float An = -expf(Alog[hd]);
    float dtbF = dtb[hd];

    // dt + inclusive cumsum (Hillis-Steele)
    {
        size_t row = (size_t)b * SEQ + ck * QS + tid;
        float xx = bf2f(zx[row * DPROJ + DTOFF + hd]) + dtbF;
        float dt = (xx > 20.f) ? xx : log1pf(expf(xx));
        sdtL[tid] = dt;
        scumL[tid] = dt;
        __syncthreads();
        for (int ofs = 1; ofs < 256; ofs <<= 1) {
            float v = scumL[tid];
            float u = (tid >= ofs) ? scumL[tid - ofs] : 0.f;
            __syncthreads();
            scumL[tid] = v + u;
            __syncthreads();
        }
        float cumQ = scumL[255];
        swL[tid] = expf(An * (cumQ - scumL[tid])) * dt;
        size_t gbase = (((size_t)b * NH + hd) * NQ + ck) * QS;
        scum_g[gbase + tid] = scumL[tid];
        sdt_g[gbase + tid] = dt;
        if (tid == 0) dAck[((size_t)b * NH + hd) * NQ + ck] = expf(An * cumQ);
    }

    f32x4 hacc[2][4];
    #pragma unroll
    for (int i = 0; i < 2; i++)
        #pragma unroll
        for (int j = 0; j < 4; j++) hacc[i][j] = (f32x4){0.f, 0.f, 0.f, 0.f};

    int n0 = wv * 32;
    int jj = tid & 127, hi = tid >> 7;

    for (int half = 0; half < 2; ++half) {
        __syncthreads();   // swL ready / previous MFMA reads done
        size_t rowj = ((size_t)b * SEQ + ck * QS + half * 128 + jj) * DPROJ;
        float wj = swL[half * 128 + jj];
        // stage Bw^T [n][j]
        #pragma unroll
        for (int it = 0; it < 8; ++it) {
            int nc = hi * 8 + it;
            uint4 v = *(const uint4*)(zx + rowj + BOFF + nc * 8);
            float f[8]; unpack8(v, f);
            #pragma unroll
            for (int u = 0; u < 8; ++u)
                BwT[(nc * 8 + u) * 136 + jj] = f2bf(f[u] * wj);
        }
        // stage X^T [p][j]
        #pragma unroll
        for (int it = 0; it < 4; ++it) {
            int pc = hi * 4 + it;
            uint4 v = *(const uint4*)(zx + rowj + XOFF + hd * 64 + pc * 8);
            const u16* vp = (const u16*)&v;
            #pragma unroll
            for (int u = 0; u < 8; ++u)
                XT1[(pc * 8 + u) * 136 + jj] = vp[u];
        }
        __syncthreads();
        #pragma unroll
        for (int kk = 0; kk < 4; ++kk) {
            bf16x8 af[2], bx[4];
            #pragma unroll
            for (int it = 0; it < 2; ++it)
                af[it] = *(const bf16x8*)&BwT[(n0 + it * 16 + mr) * 136 + kk * 32 + q * 8];
            #pragma unroll
            for (int pt = 0; pt < 4; ++pt)
                bx[pt] = *(const bf16x8*)&XT1[(pt * 16 + mr) * 136 + kk * 32 + q * 8];
            #pragma unroll
            for (int it = 0; it < 2; ++it)
                #pragma unroll
                for (int pt = 0; pt < 4; ++pt)
                    hacc[it][pt] = __builtin_amdgcn_mfma_f32_16x16x32_bf16(
                        af[it], bx[pt], hacc[it][pt], 0, 0, 0);
        }
    }

    size_t basec = (((size_t)b * NH + hd) * NQ + ck) * 8192;
    #pragma unroll
    for (int it = 0; it < 2; ++it)
        #pragma unroll
        for (int pt = 0; pt < 4; ++pt)
            #pragma unroll
            for (int reg = 0; reg < 4; ++reg) {
                int n = n0 + it * 16 + q * 4 + reg;
                int p = pt * 16 + mr;
                cs[basec + p * 128 + n] = f2bf(hacc[it][pt][reg]);
            }
}

// ================= SSD pass 2: sequential chunk combine, Hinc -> Hstart in place =================
// grid (8, NH, NBATCH), 256 threads, each owns 4 contiguous state elems.
__global__ __launch_bounds__(256) void ssd_p2(
    u16* __restrict__ cs, const float* __restrict__ dAck)
{
    int hd = blockIdx.y, b = blockIdx.z;
    int off = blockIdx.x * 1024 + threadIdx.x * 4;
    size_t base = (((size_t)b * NH + hd) * NQ) * 8192 + off;
    const float* dA = dAck + ((size_t)b * NH + hd) * NQ;
    float c0 = 0.f, c1 = 0.f, c2 = 0.f, c3 = 0.f;
    for (int ck = 0; ck < NQ; ++ck) {
        u16* p = cs + base + (size_t)ck * 8192;
        uint2 v = *(const uint2*)p;
        float i0 = bf2f((u16)(v.x & 0xFFFF)), i1 = bf2f((u16)(v.x >> 16));
        float i2 = bf2f((u16)(v.y & 0xFFFF)), i3 = bf2f((u16)(v.y >> 16));
        u16 o[4] = { f2bf(c0), f2bf(c1), f2bf(c2), f2bf(c3) };
        *(uint2*)p = *(const uint2*)o;
        float a = dA[ck];
        c0 = fmaf(a, c0, i0); c1 = fmaf(a, c1, i1);
        c2 = fmaf(a, c2, i2); c3 = fmaf(a, c3, i3);
    }
}

// ================= SSD pass 3: Y = decay.(C@Hstart) + (L.(C@B^T))@X + D.x =================
// grid (NQ, NH, NBATCH), 256 threads (4 waves x 64-row i-panels). Writes y over x cols of zx.
__global__ __launch_bounds__(256) void ssd_p3(
    u16* __restrict__ zx,
    const float* __restrict__ Alog, const float* __restrict__ Dp,
    const u16* __restrict__ cs,
    const float* __restrict__ scum_g, const float* __restrict__ sdt_g)
{
    int ck = blockIdx.x, hd = blockIdx.y, b = blockIdx.z;
    int tid = threadIdx.x;
    int wv = tid >> 6, lane = tid & 63, q = lane >> 4, mr = lane & 15;
    int i0 = wv * 64;

    __shared__ __align__(16) u16 XT[64 * 264];     // x^T [p][j], padded
    __shared__ __align__(16) u16 Mt[4 * 64 * 40];  // per-wave masked-M tiles
    __shared__ __align__(16) u16 HsB[64 * 136];    // Hstart [p][n]; reused as B j-tile [j<=32][n]
    __shared__ float scumL[256], sdtL[256];

    float An = -expf(Alog[hd]);
    float Dh = Dp[hd];

    {
        size_t gbase = (((size_t)b * NH + hd) * NQ + ck) * QS;
        scumL[tid] = scum_g[gbase + tid];
        sdtL[tid] = sdt_g[gbase + tid];
    }
    // stage X^T: thread = j, iterate p-chunks
    {
        size_t rowj = ((size_t)b * SEQ + ck * QS + tid) * DPROJ + XOFF + hd * 64;
        #pragma unroll
        for (int pc = 0; pc < 8; ++pc) {
            uint4 v = *(const uint4*)(zx + rowj + pc * 8);
            const u16* vp = (const u16*)&v;
            #pragma unroll
            for (int u = 0; u < 8; ++u)
                XT[(pc * 8 + u) * 264 + tid] = vp[u];
        }
    }
    // stage Hstart [p][n] (straight copy w/ row pad)
    {
        size_t basec = (((size_t)b * NH + hd) * NQ + ck) * 8192;
        #pragma unroll
        for (int it = 0; it < 4; ++it) {
            int c = it * 256 + tid;
            int p = c >> 4, nc = c & 15;
            uint4 v = *(const uint4*)(cs + basec + p * 128 + nc * 8);
            *(uint4*)&HsB[p * 136 + nc * 8] = v;
        }
    }
    // C fragments from global (held in registers all kernel)
    bf16x8 cfr[4][4];
    #pragma unroll
    for (int it = 0; it < 4; ++it) {
        size_t row = ((size_t)b * SEQ + ck * QS + i0 + it * 16 + mr) * DPROJ + COFF;
        #pragma unroll
        for (int kk = 0; kk < 4; ++kk)
            cfr[it][kk] = *(const bf16x8*)(zx + row + kk * 32 + q * 8);
    }

    f32x4 Y[4][4];
    #pragma unroll
    for (int i = 0; i < 4; i++)
        #pragma unroll
        for (int j = 0; j < 4; j++) Y[i][j] = (f32x4){0.f, 0.f, 0.f, 0.f};

    __syncthreads();

    // Y1 = C @ Hstart  (then scale rows by exp(An*cum_i))
    #pragma unroll
    for (int kk = 0; kk < 4; ++kk) {
        bf16x8 hb[4];
        #pragma unroll
        for (int pt = 0; pt < 4; ++pt)
            hb[pt] = *(const bf16x8*)&HsB[(pt * 16 + mr) * 136 + kk * 32 + q * 8];
        #pragma unroll
        for (int it = 0; it < 4; ++it)
            #pragma unroll
            for (int pt = 0; pt < 4; ++pt)
                Y[it][pt] = __builtin_amdgcn_mfma_f32_16x16x32_bf16(
                    cfr[it][kk], hb[pt], Y[it][pt], 0, 0, 0);
    }
    #pragma unroll
    for (int it = 0; it < 4; ++it)
        #pragma unroll
        for (int reg = 0; reg < 4; ++reg) {
            float f = expf(An * scumL[i0 + it * 16 + q * 4 + reg]);
            #pragma unroll
            for (int pt = 0; pt < 4; ++pt) Y[it][pt][reg] *= f;
        }

    // intra-chunk: stream j-tiles of 32
    for (int jt = 0; jt < 8; ++jt) {
        int jt0 = jt * 32;
        __syncthreads();   // prior HsB reads done
        // stage B j-tile [j][n] into HsB region
        #pragma unroll
        for (int it = 0; it < 2; ++it) {
            int c = it * 256 + tid;
            int j = c >> 4, nc = c & 15;
            uint4 v = *(const uint4*)(zx +
                ((size_t)b * SEQ + ck * QS + jt0 + j) * DPROJ + BOFF + nc * 8);
            *(uint4*)&HsB[j * 136 + nc * 8] = v;
        }
        __syncthreads();
        // S = C @ B^T  (64 i x 32 j per wave)
        f32x4 S[4][2];
        #pragma unroll
        for (int i = 0; i < 4; i++)
            #pragma unroll
            for (int j = 0; j < 2; j++) S[i][j] = (f32x4){0.f, 0.f, 0.f, 0.f};
        #pragma unroll
        for (int kk = 0; kk < 4; ++kk) {
            bf16x8 bb[2];
            #pragma unroll
            for (int j16 = 0; j16 < 2; ++j16)
                bb[j16] = *(const bf16x8*)&HsB[(j16 * 16 + mr) * 136 + kk * 32 + q * 8];
            #pragma unroll
            for (int it = 0; it < 4; ++it)
                #pragma unroll
                for (int j16 = 0; j16 < 2; ++j16)
                    S[it][j16] = __builtin_amdgcn_mfma_f32_16x16x32_bf16(
                        cfr[it][kk], bb[j16], S[it][j16], 0, 0, 0);
        }
        // mask + decay + dt -> M (bf16, per-wave LDS tile)
        #pragma unroll
        for (int it = 0; it < 4; ++it)
            #pragma unroll
            for (int j16 = 0; j16 < 2; ++j16)
                #pragma unroll
                for (int reg = 0; reg < 4; ++reg) {
                    int i = i0 + it * 16 + q * 4 + reg;
                    int jl = j16 * 16 + mr;
                    int jg = jt0 + jl;
                    float m = 0.f;
                    if (jg <= i)
                        m = expf(An * (scumL[i] - scumL[jg])) * sdtL[jg] * S[it][j16][reg];
                    Mt[wv * 2560 + (it * 16 + q * 4 + reg) * 40 + jl] = f2bf(m);
                }
        __syncthreads();
        // Y += M @ X
        bf16x8 mf[4];
        #pragma unroll
        for (int it = 0; it < 4; ++it)
            mf[it] = *(const bf16x8*)&Mt[wv * 2560 + (it * 16 + mr) * 40 + q * 8];
        #pragma unroll
        for (int pt = 0; pt < 4; ++pt) {
            bf16x8 xf = *(const bf16x8*)&XT[(pt * 16 + mr) * 264 + jt0 + q * 8];
            #pragma unroll
            for (int it = 0; it < 4; ++it)
                Y[it][pt] = __builtin_amdgcn_mfma_f32_16x16x32_bf16(
                    mf[it], xf, Y[it][pt], 0, 0, 0);
        }
    }

    // epilogue: y = Y + D*x, write over x cols
    #pragma unroll
    for (int it = 0; it < 4; ++it)
        #pragma unroll
        for (int pt = 0; pt < 4; ++pt)
            #pragma unroll
            for (int reg = 0; reg < 4; ++reg) {
                int i = i0 + it * 16 + q * 4 + reg;
                int p = pt * 16 + mr;
                float xv = bf2f(XT[p * 264 + i]);
                float val = Y[it][pt][reg] + Dh * xv;
                zx[((size_t)b * SEQ + ck * QS + i) * DPROJ + XOFF + hd * 64 + p] = f2bf(val);
            }
}

// ---------------- y * silu(z) then rmsnorm(gnorm_w f32); z and y both live in zx ----------------
__global__ __launch_bounds__(256) void gatenorm_kernel(
    u16* __restrict__ zx, const float* __restrict__ gw)
{
    int row = blockIdx.x, tid = threadIdx.x;
    u16* zr = zx + (size_t)row * DPROJ;
    float v[8];
    float s = 0.f;
    #pragma unroll
    for (int i = 0; i < 8; ++i) {
        int idx = i * 256 + tid;
        float zv = bf2f(zr[idx]);
        float gate = zv / (1.f + expf(-zv));
        float val = bf2f(zr[DINNER + idx]) * gate;
        v[i] = val;
        s += val * val;
    }
    #pragma unroll
    for (int off = 32; off; off >>= 1) s += __shfl_xor(s, off);
    __shared__ float red[4];
    if ((tid & 63) == 0) red[tid >> 6] = s;
    __syncthreads();
    float tot = red[0] + red[1] + red[2] + red[3];
    float sc = rsqrtf(tot * (1.f / DINNER) + 1e-5f);
    #pragma unroll
    for (int i = 0; i < 8; ++i) {
        int idx = i * 256 + tid;
        zr[DINNER + idx] = f2bf(v[i] * sc * gw[idx]);
    }
}

extern "C" void kernel_launch(void* const* d_in, const int* in_sizes, int n_in,
                              void* d_out, int out_size, void* d_ws, size_t ws_size,
                              hipStream_t stream) {
    const int*   x          = (const int*)d_in[0];
    const float* emb        = (const float*)d_in[1];
    const float* in_proj_w  = (const float*)d_in[2];
    const float* conv_w     = (const float*)d_in[3];
    const float* conv_b     = (const float*)d_in[4];
    const float* dt_bias    = (const float*)d_in[5];
    const float* A_log      = (const float*)d_in[6];
    const float* Dp         = (const float*)d_in[7];
    const float* gnorm_w    = (const float*)d_in[8];
    const float* out_proj_w = (const float*)d_in[9];
    const float* rms_w      = (const float*)d_in[10];
    const float* norm_f_w   = (const float*)d_in[11];
    const float* lm_head_w  = (const float*)d_in[12];
    float* out = (float*)d_out;

    // Workspace (~228 MB): h 32MiB | zx 137MB | scratch 32MiB (normed/halo/cs)
    // | wA 9MB | wB 4.2MB | scum_g 2MB | sdt_g 2MB | dAck 8KB
    char* w = (char*)d_ws;
    u16* h       = (u16*)w; w += (size_t)ROWS * DMODEL * 2;
    u16* zx      = (u16*)w; w += (size_t)ROWS * DPROJ * 2;
    char* scratch = w;      w += (size_t)NBATCH * NH * NQ * 8192 * 2;  // 32 MiB
    u16* wA      = (u16*)w; w += (size_t)DPROJ * DMODEL * 2;
    u16* wB      = (u16*)w; w += (size_t)DMODEL * DINNER * 2;
    float* scum_g = (float*)w; w += (size_t)NBATCH * NH * NQ * QS * 4;
    float* sdt_g  = (float*)w; w += (size_t)NBATCH * NH * NQ * QS * 4;
    float* dAck   = (float*)w; w += (size_t)NBATCH * NH * NQ * 4;
    u16* normed  = (u16*)scratch;
    u16* halo    = (u16*)scratch;
    u16* cs      = (u16*)scratch;

    embed_kernel<<<ROWS, 256, 0, stream>>>(x, emb, h);

    const int nInW = DPROJ * DMODEL;
    const int nOutW = DMODEL * DINNER;
    const int nHeadW = 64 * DMODEL;

    for (int l = 0; l < 4; ++l) {
        cvt_kernel<<<nInW / 1024, 256, 0, stream>>>(
            in_proj_w + (size_t)l * nInW, wA, nInW);
        cvt_kernel<<<nOutW / 1024, 256, 0, stream>>>(
            out_proj_w + (size_t)l * nOutW, wB, nOutW);
        rmsnorm_kernel<<<ROWS, 256, 0, stream>>>(h, rms_w + l * DMODEL, normed);
        gemm_nt<0><<<128 * 35, 256, 0, stream>>>(
            normed, wA, DPROJ, DMODEL, DMODEL, 35, zx, nullptr);
        halo_kernel<<<dim3(9, (NCH - 1) * 3, NBATCH), 256, 0, stream>>>(zx, halo);
        convip_kernel<<<dim3(9, NCH, NBATCH), 256, 0, stream>>>(
            zx, conv_w + (size_t)l * CONVD * 4, conv_b + (size_t)l * CONVD, halo);
        // SSD chunked scan (MFMA)
        ssd_p1<<<dim3(NQ, NH, NBATCH), 256, 0, stream>>>(
            zx, dt_bias + l * NH, A_log + l * NH, cs, scum_g, sdt_g, dAck);
        ssd_p2<<<dim3(8, NH, NBATCH), 256, 0, stream>>>(cs, dAck);
        ssd_p3<<<dim3(NQ, NH, NBATCH), 256, 0, stream>>>(
            zx, A_log + l * NH, Dp + l * NH, cs, scum_g, sdt_g);
        gatenorm_kernel<<<ROWS, 256, 0, stream>>>(zx, gnorm_w + (size_t)l * DINNER);
        gemm_nt<1><<<128 * 8, 256, 0, stream>>>(
            zx + DINNER, wB, DMODEL, DINNER, DPROJ, 8, h, nullptr);
    }

    rmsnorm_kernel<<<ROWS, 256, 0, stream>>>(h, norm_f_w, normed);
    cvt_kernel<<<nHeadW / 1024, 256, 0, stream>>>(lm_head_w, wA, nHeadW);
    gemm_nt<2><<<128 * 1, 256, 0, stream>>>(
        normed, wA, 64, DMODEL, DMODEL, 1, nullptr, out);
}

// Round 7
// 2645.073 us; speedup vs baseline: 3.5987x; 1.3639x over previous
//
#include <hip/hip_runtime.h>
#include <hip/hip_bf16.h>

typedef unsigned short u16;
typedef unsigned int u32;
typedef __attribute__((ext_vector_type(8))) __bf16 bf16x8;
typedef __attribute__((ext_vector_type(4))) float f32x4;

#define SEQ 4096
#define NBATCH 4
#define DMODEL 1024
#define DINNER 2048
#define DSTATE 128
#define NH 32
#define CONVD 2304
#define DPROJ 4384
#define ROWS (NBATCH*SEQ)   // 16384
#define TCH 256             // conv time-chunk
#define NCH (SEQ/TCH)       // 16 chunks -> 15 halo boundaries per batch
#define QS 256              // SSD chunk length
#define NQ (SEQ/QS)         // 16 SSD chunks
#define XOFF DINNER                   // 2048: conv'd x columns
#define BOFF (2*DINNER)               // 4096: B columns
#define COFF (2*DINNER + DSTATE)      // 4224: C columns
#define DTOFF (2*DINNER + 2*DSTATE)   // 4352: dt columns

__device__ __forceinline__ float bf2f(u16 v) {
    u32 x = ((u32)v) << 16;
    float f;
    __builtin_memcpy(&f, &x, 4);
    return f;
}
__device__ __forceinline__ u16 f2bf(float f) {
    u32 x;
    __builtin_memcpy(&x, &f, 4);
    u32 r = (x + 0x7FFFu + ((x >> 16) & 1u)) >> 16;
    return (u16)r;
}
__device__ __forceinline__ void unpack8(uint4 v, float* f) {
    u32 w0 = v.x, w1 = v.y, w2 = v.z, w3 = v.w;
    f[0] = bf2f((u16)(w0 & 0xFFFF)); f[1] = bf2f((u16)(w0 >> 16));
    f[2] = bf2f((u16)(w1 & 0xFFFF)); f[3] = bf2f((u16)(w1 >> 16));
    f[4] = bf2f((u16)(w2 & 0xFFFF)); f[5] = bf2f((u16)(w2 >> 16));
    f[6] = bf2f((u16)(w3 & 0xFFFF)); f[7] = bf2f((u16)(w3 >> 16));
}

// async global->LDS, 16B/lane: LDS dest = wave-uniform base + lane*16
__device__ __forceinline__ void async16(u16* lds_base, const u16* g) {
    __builtin_amdgcn_global_load_lds(
        (const __attribute__((address_space(1))) u32*)g,
        (__attribute__((address_space(3))) u32*)(u32)(size_t)lds_base,
        16, 0, 0);
}

// ---------------- f32 -> bf16 weight panel conversion ----------------
__global__ __launch_bounds__(256) void cvt_kernel(
    const float* __restrict__ in, u16* __restrict__ out, int n)
{
    int i = (blockIdx.x * 256 + threadIdx.x) * 4;
    if (i < n) {
        float4 v = *(const float4*)(in + i);
        u16 o[4] = { f2bf(v.x), f2bf(v.y), f2bf(v.z), f2bf(v.w) };
        *(uint2*)(out + i) = *(const uint2*)o;
    }
}

// ---------------- embedding: f32 table -> bf16 rows ----------------
__global__ __launch_bounds__(256) void embed_kernel(
    const int* __restrict__ x, const float* __restrict__ emb, u16* __restrict__ h)
{
    int row = blockIdx.x, tid = threadIdx.x;
    int id = x[row];
    float4 v = *(const float4*)(emb + (size_t)id * DMODEL + tid * 4);
    u16 o[4] = { f2bf(v.x), f2bf(v.y), f2bf(v.z), f2bf(v.w) };
    *(uint2*)(h + (size_t)row * DMODEL + tid * 4) = *(const uint2*)o;
}

// ---------------- rmsnorm (bf16 in, f32 weight -> bf16 out) ----------------
__global__ __launch_bounds__(256) void rmsnorm_kernel(
    const u16* __restrict__ in, const float* __restrict__ w, u16* __restrict__ out)
{
    int row = blockIdx.x, tid = threadIdx.x;
    const u16* r = in + (size_t)row * DMODEL + tid * 4;
    float v[4];
    v[0] = bf2f(r[0]); v[1] = bf2f(r[1]); v[2] = bf2f(r[2]); v[3] = bf2f(r[3]);
    float s = v[0]*v[0] + v[1]*v[1] + v[2]*v[2] + v[3]*v[3];
    #pragma unroll
    for (int off = 32; off; off >>= 1) s += __shfl_xor(s, off);
    __shared__ float red[4];
    if ((tid & 63) == 0) red[tid >> 6] = s;
    __syncthreads();
    float tot = red[0] + red[1] + red[2] + red[3];
    float sc = rsqrtf(tot * (1.f / DMODEL) + 1e-5f);
    float4 wv = *(const float4*)(w + tid * 4);
    u16* o = out + (size_t)row * DMODEL + tid * 4;
    u16 ov[4] = { f2bf(v[0] * sc * wv.x), f2bf(v[1] * sc * wv.y),
                  f2bf(v[2] * sc * wv.z), f2bf(v[3] * sc * wv.w) };
    *(uint2*)o = *(const uint2*)ov;
}

// ---------------- NT GEMM: C[M,N] = A[M,K] @ B[N,K]^T, bf16 in, fp32 acc ----------------
// global_load_lds staging (16B/lane); XOR swizzle folded into per-lane global column.
template<int EPI>
__global__ __launch_bounds__(256) void gemm_nt(
    const u16* __restrict__ A, const u16* __restrict__ B,
    int N, int K, int lda, int ntiles,
    u16* __restrict__ Cb, float* __restrict__ Cf)
{
    __shared__ __align__(16) u16 As[128 * 64];
    __shared__ __align__(16) u16 Bs[128 * 64];
    const int GM = 8;
    int gsz = GM * ntiles;
    int bid = blockIdx.x;
    int grp = bid / gsz, rem = bid % gsz;
    int m0 = (grp * GM + (rem % GM)) * 128;
    int n0 = (rem / GM) * 128;

    int tid = threadIdx.x;
    int lane = tid & 63, wv = tid >> 6;
    int wm = wv & 1, wn = wv >> 1;
    int q = lane >> 4, mr = lane & 15;

    f32x4 acc[4][4];
    #pragma unroll
    for (int i = 0; i < 4; i++)
        #pragma unroll
        for (int j = 0; j < 4; j++) acc[i][j] = (f32x4){0.f, 0.f, 0.f, 0.f};

    for (int kt = 0; kt < K; kt += 64) {
        #pragma unroll
        for (int ps = 0; ps < 4; ++ps) {
            int rb = ps * 32 + wv * 8;
            int r = rb + (lane >> 3);
            int scl = (lane & 7) ^ (r & 7);
            async16(&As[rb * 64], A + (size_t)(m0 + r) * lda + kt + scl * 8);
        }
        #pragma unroll
        for (int ps = 0; ps < 4; ++ps) {
            int rb = ps * 32 + wv * 8;
            int r = rb + (lane >> 3);
            int scl = (lane & 7) ^ (r & 7);
            int gn = n0 + r;
            if (gn < N)
                async16(&Bs[rb * 64], B + (size_t)gn * K + kt + scl * 8);
        }
        __syncthreads();
        #pragma unroll
        for (int kk = 0; kk < 2; ++kk) {
            bf16x8 af[4], bfr[4];
            #pragma unroll
            for (int mi = 0; mi < 4; ++mi) {
                int r = wm * 64 + mi * 16 + mr;
                int c = (kk * 4 + q) ^ (r & 7);
                af[mi] = *(const bf16x8*)&As[r * 64 + c * 8];
            }
            #pragma unroll
            for (int ni = 0; ni < 4; ++ni) {
                int r = wn * 64 + ni * 16 + mr;
                int c = (kk * 4 + q) ^ (r & 7);
                bfr[ni] = *(const bf16x8*)&Bs[r * 64 + c * 8];
            }
            #pragma unroll
            for (int mi = 0; mi < 4; ++mi)
                #pragma unroll
                for (int ni = 0; ni < 4; ++ni)
                    acc[mi][ni] = __builtin_amdgcn_mfma_f32_16x16x32_bf16(
                        af[mi], bfr[ni], acc[mi][ni], 0, 0, 0);
        }
        __syncthreads();
    }

    #pragma unroll
    for (int mi = 0; mi < 4; ++mi) {
        #pragma unroll
        for (int ni = 0; ni < 4; ++ni) {
            int gn = n0 + wn * 64 + ni * 16 + mr;
            if (gn < N) {
                #pragma unroll
                for (int r4 = 0; r4 < 4; ++r4) {
                    int gm = m0 + wm * 64 + mi * 16 + q * 4 + r4;
                    float v = acc[mi][ni][r4];
                    size_t idx = (size_t)gm * N + gn;
                    if (EPI == 0)      Cb[idx] = f2bf(v);
                    else if (EPI == 1) Cb[idx] = f2bf(bf2f(Cb[idx]) + v);
                    else               Cf[idx] = v;
                }
            }
        }
    }
}

// ---------------- halo save ----------------
__global__ __launch_bounds__(256) void halo_kernel(
    const u16* __restrict__ zx, u16* __restrict__ halo)
{
    int c = blockIdx.x * 256 + threadIdx.x;
    int idx = blockIdx.y;
    int b = blockIdx.z;
    int bi = idx / 3, r = idx % 3;
    int t = (bi + 1) * TCH - 3 + r;
    halo[(((size_t)b * (NCH - 1) + bi) * 3 + r) * CONVD + c] =
        zx[((size_t)b * SEQ + t) * DPROJ + DINNER + c];
}

// ---------------- depthwise causal conv + silu, in-place ----------------
__global__ __launch_bounds__(256) void convip_kernel(
    u16* __restrict__ zx, const float* __restrict__ cw, const float* __restrict__ cb,
    const u16* __restrict__ halo)
{
    int c = blockIdx.x * 256 + threadIdx.x;
    int ci = blockIdx.y;
    int b = blockIdx.z;
    float w0 = cw[c * 4 + 0], w1 = cw[c * 4 + 1];
    float w2 = cw[c * 4 + 2], w3 = cw[c * 4 + 3];
    float bias = cb[c];
    float h3 = 0.f, h2 = 0.f, h1 = 0.f;
    if (ci > 0) {
        const u16* hb = halo + (((size_t)b * (NCH - 1) + (ci - 1)) * 3) * CONVD + c;
        h3 = bf2f(hb[0 * CONVD]);
        h2 = bf2f(hb[1 * CONVD]);
        h1 = bf2f(hb[2 * CONVD]);
    }
    u16* p = zx + ((size_t)b * SEQ + (size_t)ci * TCH) * DPROJ + DINNER + c;
    #pragma unroll 4
    for (int t = 0; t < TCH; ++t) {
        float xr = bf2f(*p);
        float v = bias + w0 * h3 + w1 * h2 + w2 * h1 + w3 * xr;
        *p = f2bf(v / (1.f + expf(-v)));
        h3 = h2; h2 = h1; h1 = xr;
        p += DPROJ;
    }
}

// ================= SSD pass 1: per-chunk Hinc = Bw^T @ X (MFMA), dt cumsum =================
__global__ __launch_bounds__(256) void ssd_p1(
    const u16* __restrict__ zx,
    const float* __restrict__ dtb, const float* __restrict__ Alog,
    u16* __restrict__ cs, float* __restrict__ scum_g, float* __restrict__ sdt_g,
    float* __restrict__ dAck)
{
    int ck = blockIdx.x, hd = blockIdx.y, b = blockIdx.z;
    int tid = threadIdx.x;
    int wv = tid >> 6, lane = tid & 63, q = lane >> 4, mr = lane & 15;

    __shared__ __align__(16) u16 BwT[128 * 136];
    __shared__ __align__(16) u16 XT1[64 * 136];
    __shared__ float scumL[256], sdtL[256], swL[256];

    float An = -expf(Alog[hd]);
    float dtbF = dtb[hd];

    {
        size_t row = (size_t)b * SEQ + ck * QS + tid;
        float xx = bf2f(zx[row * DPROJ + DTOFF + hd]) + dtbF;
        float dt = (xx > 20.f) ? xx : log1pf(expf(xx));
        sdtL[tid] = dt;
        scumL[tid] = dt;
        __syncthreads();
        for (int ofs = 1; ofs < 256; ofs <<= 1) {
            float v = scumL[tid];
            float u = (tid >= ofs) ? scumL[tid - ofs] : 0.f;
            __syncthreads();
            scumL[tid] = v + u;
            __syncthreads();
        }
        float cumQ = scumL[255];
        swL[tid] = expf(An * (cumQ - scumL[tid])) * dt;
        size_t gbase = (((size_t)b * NH + hd) * NQ + ck) * QS;
        scum_g[gbase + tid] = scumL[tid];
        sdt_g[gbase + tid] = dt;
        if (tid == 0) dAck[((size_t)b * NH + hd) * NQ + ck] = expf(An * cumQ);
    }

    f32x4 hacc[2][4];
    #pragma unroll
    for (int i = 0; i < 2; i++)
        #pragma unroll
        for (int j = 0; j < 4; j++) hacc[i][j] = (f32x4){0.f, 0.f, 0.f, 0.f};

    int n0 = wv * 32;
    int jj = tid & 127, hi = tid >> 7;

    for (int half = 0; half < 2; ++half) {
        __syncthreads();
        size_t rowj = ((size_t)b * SEQ + ck * QS + half * 128 + jj) * DPROJ;
        float wj = swL[half * 128 + jj];
        #pragma unroll
        for (int it = 0; it < 8; ++it) {
            int nc = hi * 8 + it;
            uint4 v = *(const uint4*)(zx + rowj + BOFF + nc * 8);
            float f[8]; unpack8(v, f);
            #pragma unroll
            for (int u = 0; u < 8; ++u)
                BwT[(nc * 8 + u) * 136 + jj] = f2bf(f[u] * wj);
        }
        #pragma unroll
        for (int it = 0; it < 4; ++it) {
            int pc = hi * 4 + it;
            uint4 v = *(const uint4*)(zx + rowj + XOFF + hd * 64 + pc * 8);
            const u16* vp = (const u16*)&v;
            #pragma unroll
            for (int u = 0; u < 8; ++u)
                XT1[(pc * 8 + u) * 136 + jj] = vp[u];
        }
        __syncthreads();
        #pragma unroll
        for (int kk = 0; kk < 4; ++kk) {
            bf16x8 af[2], bx[4];
            #pragma unroll
            for (int it = 0; it < 2; ++it)
                af[it] = *(const bf16x8*)&BwT[(n0 + it * 16 + mr) * 136 + kk * 32 + q * 8];
            #pragma unroll
            for (int pt = 0; pt < 4; ++pt)
                bx[pt] = *(const bf16x8*)&XT1[(pt * 16 + mr) * 136 + kk * 32 + q * 8];
            #pragma unroll
            for (int it = 0; it < 2; ++it)
                #pragma unroll
                for (int pt = 0; pt < 4; ++pt)
                    hacc[it][pt] = __builtin_amdgcn_mfma_f32_16x16x32_bf16(
                        af[it], bx[pt], hacc[it][pt], 0, 0, 0);
        }
    }

    size_t basec = (((size_t)b * NH + hd) * NQ + ck) * 8192;
    #pragma unroll
    for (int it = 0; it < 2; ++it)
        #pragma unroll
        for (int pt = 0; pt < 4; ++pt)
            #pragma unroll
            for (int reg = 0; reg < 4; ++reg) {
                int n = n0 + it * 16 + q * 4 + reg;
                int p = pt * 16 + mr;
                cs[basec + p * 128 + n] = f2bf(hacc[it][pt][reg]);
            }
}

// ================= SSD pass 2: sequential chunk combine, Hinc -> Hstart =================
__global__ __launch_bounds__(256) void ssd_p2(
    u16* __restrict__ cs, const float* __restrict__ dAck)
{
    int hd = blockIdx.y, b = blockIdx.z;
    int off = blockIdx.x * 1024 + threadIdx.x * 4;
    size_t base = (((size_t)b * NH + hd) * NQ) * 8192 + off;
    const float* dA = dAck + ((size_t)b * NH + hd) * NQ;
    float c0 = 0.f, c1 = 0.f, c2 = 0.f, c3 = 0.f;
    for (int ck = 0; ck < NQ; ++ck) {
        u16* p = cs + base + (size_t)ck * 8192;
        uint2 v = *(const uint2*)p;
        float i0 = bf2f((u16)(v.x & 0xFFFF)), i1 = bf2f((u16)(v.x >> 16));
        float i2 = bf2f((u16)(v.y & 0xFFFF)), i3 = bf2f((u16)(v.y >> 16));
        u16 o[4] = { f2bf(c0), f2bf(c1), f2bf(c2), f2bf(c3) };
        *(uint2*)p = *(const uint2*)o;
        float a = dA[ck];
        c0 = fmaf(a, c0, i0); c1 = fmaf(a, c1, i1);
        c2 = fmaf(a, c2, i2); c3 = fmaf(a, c3, i3);
    }
}

// ================= SSD pass 3 (barrier-free jt loop) =================
// grid (NQ, NH, NBATCH). Wave wv owns i-panel [wv*64, wv*64+64).
// S^T = B@C^T with operands direct from global; C-layout->A-layout via shuffles;
// decay factorized R_i*Q_j per j-tile; waves skip fully-masked tiles.
__global__ __launch_bounds__(256, 3) void ssd_p3(
    u16* __restrict__ zx,
    const float* __restrict__ Alog, const float* __restrict__ Dp,
    const u16* __restrict__ cs,
    const float* __restrict__ scum_g, const float* __restrict__ sdt_g)
{
    int ck = blockIdx.x, hd = blockIdx.y, b = blockIdx.z;
    int tid = threadIdx.x;
    int wv = tid >> 6, lane = tid & 63, q = lane >> 4, mr = lane & 15;
    int i0 = wv * 64;

    __shared__ __align__(16) u16 XT[64 * 264];   // x^T [p][j], pad 8
    __shared__ float scumL[256], sdtL[256];

    float An = -expf(Alog[hd]);
    float Dh = Dp[hd];

    {
        size_t gbase = (((size_t)b * NH + hd) * NQ + ck) * QS;
        scumL[tid] = scum_g[gbase + tid];
        sdtL[tid] = sdt_g[gbase + tid];
    }
    // stage X^T (thread = column j)
    {
        size_t rowj = ((size_t)b * SEQ + ck * QS + tid) * DPROJ + XOFF + hd * 64;
        #pragma unroll
        for (int pc = 0; pc < 8; ++pc) {
            uint4 v = *(const uint4*)(zx + rowj + pc * 8);
            const u16* vp = (const u16*)&v;
            #pragma unroll
            for (int u = 0; u < 8; ++u)
                XT[(pc * 8 + u) * 264 + tid] = vp[u];
        }
    }

    f32x4 Y[4][4];
    #pragma unroll
    for (int i = 0; i < 4; i++)
        #pragma unroll
        for (int j = 0; j < 4; j++) Y[i][j] = (f32x4){0.f, 0.f, 0.f, 0.f};

    const size_t rowC = ((size_t)b * SEQ + ck * QS) * DPROJ;
    size_t basec = (((size_t)b * NH + hd) * NQ + ck) * 8192;

    __syncthreads();   // the only barrier

    // Y1 = C @ Hstart (both operands direct from global), then row-decay scale
    #pragma unroll
    for (int kk = 0; kk < 4; ++kk) {
        bf16x8 cf[4], hb[4];
        #pragma unroll
        for (int it = 0; it < 4; ++it)
            cf[it] = *(const bf16x8*)(zx + rowC + (size_t)(i0 + it * 16 + mr) * DPROJ
                                      + COFF + kk * 32 + q * 8);
        #pragma unroll
        for (int pt = 0; pt < 4; ++pt)
            hb[pt] = *(const bf16x8*)(cs + basec + (size_t)(pt * 16 + mr) * 128
                                      + kk * 32 + q * 8);
        #pragma unroll
        for (int it = 0; it < 4; ++it)
            #pragma unroll
            for (int pt = 0; pt < 4; ++pt)
                Y[it][pt] = __builtin_amdgcn_mfma_f32_16x16x32_bf16(
                    cf[it], hb[pt], Y[it][pt], 0, 0, 0);
    }
    #pragma unroll
    for (int it = 0; it < 4; ++it)
        #pragma unroll
        for (int reg = 0; reg < 4; ++reg) {
            float f = expf(An * scumL[i0 + it * 16 + q * 4 + reg]);
            #pragma unroll
            for (int pt = 0; pt < 4; ++pt) Y[it][pt][reg] *= f;
        }

    // intra-chunk causal part: wave-local j-tiles of 32, no barriers
    int jtmax = 2 * wv + 2;
    for (int jt = 0; jt < jtmax; ++jt) {
        int jt0 = jt * 32;
        float ref = scumL[jt0 + 15];

        // S^T[j][i] = B @ C^T, operands direct from global (L1-hot)
        f32x4 ST[2][4];
        #pragma unroll
        for (int jm = 0; jm < 2; ++jm)
            #pragma unroll
            for (int it = 0; it < 4; ++it) ST[jm][it] = (f32x4){0.f, 0.f, 0.f, 0.f};
        #pragma unroll
        for (int kk = 0; kk < 4; ++kk) {
            bf16x8 ba[2], cf[4];
            #pragma unroll
            for (int jm = 0; jm < 2; ++jm)
                ba[jm] = *(const bf16x8*)(zx + rowC + (size_t)(jt0 + jm * 16 + mr) * DPROJ
                                          + BOFF + kk * 32 + q * 8);
            #pragma unroll
            for (int it = 0; it < 4; ++it)
                cf[it] = *(const bf16x8*)(zx + rowC + (size_t)(i0 + it * 16 + mr) * DPROJ
                                          + COFF + kk * 32 + q * 8);
            #pragma unroll
            for (int jm = 0; jm < 2; ++jm)
                #pragma unroll
                for (int it = 0; it < 4; ++it)
                    ST[jm][it] = __builtin_amdgcn_mfma_f32_16x16x32_bf16(
                        ba[jm], cf[it], ST[jm][it], 0, 0, 0);
        }

        // decay factors: Q_j (lanes 0..31 domain), R_i per it
        int jq = jt0 + (lane & 31);
        float Qv = expf(An * (ref - scumL[jq])) * sdtL[jq];
        float Rit[4];
        #pragma unroll
        for (int it = 0; it < 4; ++it)
            Rit[it] = expf(An * (scumL[i0 + it * 16 + mr] - ref));

        bf16x8 xf[4];
        #pragma unroll
        for (int pt = 0; pt < 4; ++pt)
            xf[pt] = *(const bf16x8*)&XT[(pt * 16 + mr) * 264 + jt0 + q * 8];

        // assemble M A-frags (shuffle transpose of S^T) and accumulate Y += M @ X
        #pragma unroll
        for (int it = 0; it < 4; ++it) {
            u16 marr[8];
            #pragma unroll
            for (int u = 0; u < 8; ++u) {
                int src = (2 * (q & 1) + (u >> 2)) * 16 + mr;
                float s0 = __shfl(ST[0][it][u & 3], src);
                float s1 = __shfl(ST[1][it][u & 3], src);
                float sj = (q < 2) ? s0 : s1;
                float Qu = __shfl(Qv, 8 * q + u);
                int jg = jt0 + 8 * q + u;
                int ig = i0 + it * 16 + mr;
                float m = (jg <= ig) ? Rit[it] * Qu * sj : 0.f;
                marr[u] = f2bf(m);
            }
            bf16x8 mf;
            __builtin_memcpy(&mf, marr, 16);
            #pragma unroll
            for (int pt = 0; pt < 4; ++pt)
                Y[it][pt] = __builtin_amdgcn_mfma_f32_16x16x32_bf16(
                    mf, xf[pt], Y[it][pt], 0, 0, 0);
        }
    }

    // epilogue: y = Y + D*x, write over x cols
    #pragma unroll
    for (int it = 0; it < 4; ++it)
        #pragma unroll
        for (int pt = 0; pt < 4; ++pt)
            #pragma unroll
            for (int reg = 0; reg < 4; ++reg) {
                int i = i0 + it * 16 + q * 4 + reg;
                int p = pt * 16 + mr;
                float xv = bf2f(XT[p * 264 + i]);
                float val = Y[it][pt][reg] + Dh * xv;
                zx[((size_t)b * SEQ + ck * QS + i) * DPROJ + XOFF + hd * 64 + p] = f2bf(val);
            }
}

// ---------------- y * silu(z) then rmsnorm(gnorm_w f32) ----------------
__global__ __launch_bounds__(256) void gatenorm_kernel(
    u16* __restrict__ zx, const float* __restrict__ gw)
{
    int row = blockIdx.x, tid = threadIdx.x;
    u16* zr = zx + (size_t)row * DPROJ;
    float v[8];
    float s = 0.f;
    #pragma unroll
    for (int i = 0; i < 8; ++i) {
        int idx = i * 256 + tid;
        float zv = bf2f(zr[idx]);
        float gate = zv / (1.f + expf(-zv));
        float val = bf2f(zr[DINNER + idx]) * gate;
        v[i] = val;
        s += val * val;
    }
    #pragma unroll
    for (int off = 32; off; off >>= 1) s += __shfl_xor(s, off);
    __shared__ float red[4];
    if ((tid & 63) == 0) red[tid >> 6] = s;
    __syncthreads();
    float tot = red[0] + red[1] + red[2] + red[3];
    float sc = rsqrtf(tot * (1.f / DINNER) + 1e-5f);
    #pragma unroll
    for (int i = 0; i < 8; ++i) {
        int idx = i * 256 + tid;
        zr[DINNER + idx] = f2bf(v[i] * sc * gw[idx]);
    }
}

extern "C" void kernel_launch(void* const* d_in, const int* in_sizes, int n_in,
                              void* d_out, int out_size, void* d_ws, size_t ws_size,
                              hipStream_t stream) {
    const int*   x          = (const int*)d_in[0];
    const float* emb        = (const float*)d_in[1];
    const float* in_proj_w  = (const float*)d_in[2];
    const float* conv_w     = (const float*)d_in[3];
    const float* conv_b     = (const float*)d_in[4];
    const float* dt_bias    = (const float*)d_in[5];
    const float* A_log      = (const float*)d_in[6];
    const float* Dp         = (const float*)d_in[7];
    const float* gnorm_w    = (const float*)d_in[8];
    const float* out_proj_w = (const float*)d_in[9];
    const float* rms_w      = (const float*)d_in[10];
    const float* norm_f_w   = (const float*)d_in[11];
    const float* lm_head_w  = (const float*)d_in[12];
    float* out = (float*)d_out;

    char* w = (char*)d_ws;
    u16* h       = (u16*)w; w += (size_t)ROWS * DMODEL * 2;
    u16* zx      = (u16*)w; w += (size_t)ROWS * DPROJ * 2;
    char* scratch = w;      w += (size_t)NBATCH * NH * NQ * 8192 * 2;  // 32 MiB
    u16* wA      = (u16*)w; w += (size_t)DPROJ * DMODEL * 2;
    u16* wB      = (u16*)w; w += (size_t)DMODEL * DINNER * 2;
    float* scum_g = (float*)w; w += (size_t)NBATCH * NH * NQ * QS * 4;
    float* sdt_g  = (float*)w; w += (size_t)NBATCH * NH * NQ * QS * 4;
    float* dAck   = (float*)w; w += (size_t)NBATCH * NH * NQ * 4;
    u16* normed  = (u16*)scratch;
    u16* halo    = (u16*)scratch;
    u16* cs      = (u16*)scratch;

    embed_kernel<<<ROWS, 256, 0, stream>>>(x, emb, h);

    const int nInW = DPROJ * DMODEL;
    const int nOutW = DMODEL * DINNER;
    const int nHeadW = 64 * DMODEL;

    for (int l = 0; l < 4; ++l) {
        cvt_kernel<<<nInW / 1024, 256, 0, stream>>>(
            in_proj_w + (size_t)l * nInW, wA, nInW);
        cvt_kernel<<<nOutW / 1024, 256, 0, stream>>>(
            out_proj_w + (size_t)l * nOutW, wB, nOutW);
        rmsnorm_kernel<<<ROWS, 256, 0, stream>>>(h, rms_w + l * DMODEL, normed);
        gemm_nt<0><<<128 * 35, 256, 0, stream>>>(
            normed, wA, DPROJ, DMODEL, DMODEL, 35, zx, nullptr);
        halo_kernel<<<dim3(9, (NCH - 1) * 3, NBATCH), 256, 0, stream>>>(zx, halo);
        convip_kernel<<<dim3(9, NCH, NBATCH), 256, 0, stream>>>(
            zx, conv_w + (size_t)l * CONVD * 4, conv_b + (size_t)l * CONVD, halo);
        ssd_p1<<<dim3(NQ, NH, NBATCH), 256, 0, stream>>>(
            zx, dt_bias + l * NH, A_log + l * NH, cs, scum_g, sdt_g, dAck);
        ssd_p2<<<dim3(8, NH, NBATCH), 256, 0, stream>>>(cs, dAck);
        ssd_p3<<<dim3(NQ, NH, NBATCH), 256, 0, stream>>>(
            zx, A_log + l * NH, Dp + l * NH, cs, scum_g, sdt_g);
        gatenorm_kernel<<<ROWS, 256, 0, stream>>>(zx, gnorm_w + (size_t)l * DINNER);
        gemm_nt<1><<<128 * 8, 256, 0, stream>>>(
            zx + DINNER, wB, DMODEL, DINNER, DPROJ, 8, h, nullptr);
    }

    rmsnorm_kernel<<<ROWS, 256, 0, stream>>>(h, norm_f_w, normed);
    cvt_kernel<<<nHeadW / 1024, 256, 0, stream>>>(lm_head_w, wA, nHeadW);
    gemm_nt<2><<<128 * 1, 256, 0, stream>>>(
        normed, wA, 64, DMODEL, DMODEL, 1, nullptr, out);
}